// Round 12
// baseline (4857.147 us; speedup 1.0000x reference)
//
#include <hip/hip_runtime.h>
#include <hip/hip_bf16.h>
#include <hip/hip_fp16.h>
#include <stdint.h>

// Problem dims
#define BB 128
#define TT 512
#define HH 256
#define VV 29
#define NSTEP 63
#define BT (BB*TT)
#define CHUNK 64   // layer-1 time chunk
#define GQ 4       // decoder WGs per batch

typedef _Float16 f16;
typedef _Float16 f16x2 __attribute__((ext_vector_type(2)));
typedef _Float16 f16x8 __attribute__((ext_vector_type(8)));
typedef float f32x4 __attribute__((ext_vector_type(4)));
typedef unsigned long long u64;

static __device__ __forceinline__ float fdot2u(uint32_t a, uint32_t b, float c) {
  return __builtin_amdgcn_fdot2(__builtin_bit_cast(f16x2, a),
                                __builtin_bit_cast(f16x2, b), c, false);
}
static __device__ __forceinline__ float sigm_(float x) {
  return 1.0f / (1.0f + __expf(-x));
}
// tagged exchange: (tag<<32)|payload32 in one relaxed agent-scope atomic.
// Publish via atomic exchange (executes at coherence point, no L2 invalidate).
// Poll with s_sleep backoff.
static __device__ __forceinline__ void pubp(u64* p, unsigned tag, uint32_t pay) {
  u64 pkt = ((u64)tag << 32) | (u64)pay;
  (void)__hip_atomic_exchange(p, pkt, __ATOMIC_RELAXED, __HIP_MEMORY_SCOPE_AGENT);
}
static __device__ __forceinline__ uint32_t pollp(const u64* p, unsigned tag) {
  u64 pkt = __hip_atomic_load(p, __ATOMIC_RELAXED, __HIP_MEMORY_SCOPE_AGENT);
  while ((unsigned)(pkt >> 32) < tag) {
    __builtin_amdgcn_s_sleep(8);
    pkt = __hip_atomic_load(p, __ATOMIC_RELAXED, __HIP_MEMORY_SCOPE_AGENT);
  }
  return (uint32_t)pkt;
}
static __device__ __forceinline__ void pubf(u64* p, unsigned tag, float v) {
  pubp(p, tag, __builtin_bit_cast(uint32_t, v));
}
static __device__ __forceinline__ float pollf(const u64* p, unsigned tag) {
  return __builtin_bit_cast(float, pollp(p, tag));
}
static __device__ __forceinline__ uint32_t pack2h(float a, float b) {
  unsigned short ua = __builtin_bit_cast(unsigned short, (f16)a);
  unsigned short ub = __builtin_bit_cast(unsigned short, (f16)b);
  return (uint32_t)ua | ((uint32_t)ub << 16);
}

// ---------------- fp32 -> f16 convert ----------------
__global__ void k_cvt(const float* __restrict__ s, f16* __restrict__ d, int n) {
  int i = blockIdx.x * 256 + threadIdx.x;
  if (i < n) d[i] = (f16)s[i];
}

// ---------------- persistent GRU scan: 1 WG per (batch, dir) ----------------
// h double-buffered in LDS -> ONE barrier per step.
template<int LAYER>
__global__ __launch_bounds__(512, 2)
void k_scan(const float* __restrict__ x,        // L0: (B,T,2)
            const f16* __restrict__ gi,         // L1: (B,nsteps,1536) chunk-local
            const uint32_t* __restrict__ whh,   // (2,768,128) as half2
            const float* __restrict__ wih0,     // L0: (2,768,2)
            const float* __restrict__ bih,      // L0: (2,768)
            const float* __restrict__ bhh,      // (2,768)
            f16* __restrict__ y,                // (B,T,512) [t][dir*256+p]
            float* __restrict__ hstate,         // (2,B,256) f32
            int t0, int nsteps)
{
  const int wg = blockIdx.x, b = wg >> 1, dir = wg & 1;
  const int tid = threadIdx.x, pair = tid >> 1, half = tid & 1;
  __shared__ __align__(16) uint4 hv4[2][32];   // h as f16[256], double-buffered

  uint4 w0[16], w1[16], w2[16];
  {
    const uint32_t* wp = whh + (size_t)dir * 768 * 128;
    const uint4* r0 = (const uint4*)(wp + (size_t)pair * 128 + half * 64);
    const uint4* r1 = (const uint4*)(wp + (size_t)(pair + 256) * 128 + half * 64);
    const uint4* r2 = (const uint4*)(wp + (size_t)(pair + 512) * 128 + half * 64);
#pragma unroll
    for (int i = 0; i < 16; i++) { w0[i] = r0[i]; w1[i] = r1[i]; w2[i] = r2[i]; }
  }
  const float bh0 = bhh[dir * 768 + pair];
  const float bh1 = bhh[dir * 768 + pair + 256];
  const float bh2 = bhh[dir * 768 + pair + 512];
  float bi0 = 0, bi1 = 0, bi2 = 0;
  float wi00 = 0, wi01 = 0, wi10 = 0, wi11 = 0, wi20 = 0, wi21 = 0;
  if (LAYER == 0) {
    bi0 = bih[dir * 768 + pair];
    bi1 = bih[dir * 768 + pair + 256];
    bi2 = bih[dir * 768 + pair + 512];
    wi00 = wih0[(dir * 768 + pair) * 2 + 0];
    wi01 = wih0[(dir * 768 + pair) * 2 + 1];
    wi10 = wih0[(dir * 768 + pair + 256) * 2 + 0];
    wi11 = wih0[(dir * 768 + pair + 256) * 2 + 1];
    wi20 = wih0[(dir * 768 + pair + 512) * 2 + 0];
    wi21 = wih0[(dir * 768 + pair + 512) * 2 + 1];
  }
  float* hs = hstate + ((size_t)dir * BB + b) * 256;
  float hreg = hs[pair];
  if (tid < 128) {
    f16x2 p2; p2[0] = (f16)hs[2 * tid]; p2[1] = (f16)hs[2 * tid + 1];
    ((uint32_t*)hv4[0])[tid] = __builtin_bit_cast(uint32_t, p2);
  }
  __syncthreads();

  int cb = 0;
  for (int s = 0; s < nsteps; ++s) {
    const int t = dir ? (TT - 1 - t0 - s) : (t0 + s);
    float gr, gz, gn;
    if (LAYER == 0) {
      float x0 = x[((size_t)b * TT + t) * 2 + 0];
      float x1 = x[((size_t)b * TT + t) * 2 + 1];
      gr = wi00 * x0 + wi01 * x1 + bi0;
      gz = wi10 * x0 + wi11 * x1 + bi1;
      gn = wi20 * x0 + wi21 * x1 + bi2;
    } else {
      const f16* g = gi + ((size_t)b * nsteps + s) * 1536 + dir * 768 + pair;
      gr = (float)g[0]; gz = (float)g[256]; gn = (float)g[512];
    }
    const uint4* hw = hv4[cb] + half * 16;
    float a0 = 0.f, a1 = 0.f, a2 = 0.f;
#pragma unroll
    for (int j = 0; j < 16; ++j) {
      uint4 hh = hw[j];
      a0 = fdot2u(w0[j].x, hh.x, a0); a0 = fdot2u(w0[j].y, hh.y, a0);
      a0 = fdot2u(w0[j].z, hh.z, a0); a0 = fdot2u(w0[j].w, hh.w, a0);
      a1 = fdot2u(w1[j].x, hh.x, a1); a1 = fdot2u(w1[j].y, hh.y, a1);
      a1 = fdot2u(w1[j].z, hh.z, a1); a1 = fdot2u(w1[j].w, hh.w, a1);
      a2 = fdot2u(w2[j].x, hh.x, a2); a2 = fdot2u(w2[j].y, hh.y, a2);
      a2 = fdot2u(w2[j].z, hh.z, a2); a2 = fdot2u(w2[j].w, hh.w, a2);
    }
    a0 += __shfl_xor(a0, 1);
    a1 += __shfl_xor(a1, 1);
    a2 += __shfl_xor(a2, 1);

    float r = sigm_(gr + a0 + bh0);
    float z = sigm_(gz + a1 + bh1);
    float n = tanhf(gn + r * (a2 + bh2));
    float hn = (1.0f - z) * n + z * hreg;
    hreg = hn;
    if (half == 0) {
      y[((size_t)b * TT + t) * 512 + dir * 256 + pair] = (f16)hn;
      ((f16*)hv4[cb ^ 1])[pair] = (f16)hn;   // write OTHER buffer
    }
    __syncthreads();  // nxt buffer complete; cur reads all done (pre-barrier)
    cb ^= 1;
  }
  if (half == 0) hs[pair] = hreg;
}

// ---------------- f16 MFMA GEMM: C = Arows @ Bt^T + bias ---------------------
__global__ __launch_bounds__(256)
void k_gemm(const f16* __restrict__ A, const f16* __restrict__ Bt,
            f16* __restrict__ C, const float* __restrict__ bias,
            int K, int shift, long bstride, int inner, int ldc, int coloff)
{
  const int m0 = blockIdx.x * 64, n0 = blockIdx.y * 64;
  const int tid = threadIdx.x, lane = tid & 63, wv = tid >> 6;
  __shared__ __align__(16) f16 As[64 * 40];
  __shared__ __align__(16) f16 Bs[64 * 40];
  f32x4 acc[4] = {{0,0,0,0},{0,0,0,0},{0,0,0,0},{0,0,0,0}};
  const int lrow = tid >> 2, lseg = tid & 3;
  const int ml = lane & 15, quad = lane >> 4;
  const int r = m0 + lrow;
  const f16* arow = A + (long)(r >> shift) * bstride
                      + (long)(r & ((1 << shift) - 1)) * inner;
  const f16* brow = Bt + (size_t)(n0 + lrow) * K;
  for (int k0 = 0; k0 < K; k0 += 32) {
    uint4 av = *(const uint4*)(arow + k0 + lseg * 8);
    uint4 bv = *(const uint4*)(brow + k0 + lseg * 8);
    __syncthreads();
    *(uint4*)(As + lrow * 40 + lseg * 8) = av;
    *(uint4*)(Bs + lrow * 40 + lseg * 8) = bv;
    __syncthreads();
    f16x8 af = *(const f16x8*)(As + (wv * 16 + ml) * 40 + quad * 8);
#pragma unroll
    for (int ns = 0; ns < 4; ++ns) {
      f16x8 bf = *(const f16x8*)(Bs + (ns * 16 + ml) * 40 + quad * 8);
      acc[ns] = __builtin_amdgcn_mfma_f32_16x16x32_f16(af, bf, acc[ns], 0, 0, 0);
    }
  }
#pragma unroll
  for (int ns = 0; ns < 4; ++ns) {
#pragma unroll
    for (int rr = 0; rr < 4; ++rr) {
      int row = m0 + wv * 16 + quad * 4 + rr;
      int col = n0 + ns * 16 + ml;
      float v = acc[ns][rr];
      if (bias) v += bias[col];
      C[(size_t)row * ldc + coloff + col] = (f16)v;
    }
  }
}

// ---------------- gi0[v][row] = dWih0 @ emb[v] + dbih  (29 x 768, f32) -------
__global__ void k_gi0(const float* __restrict__ dWih0, const float* __restrict__ dbih,
                      const float* __restrict__ emb, float* __restrict__ gi0) {
  int i = blockIdx.x * 256 + threadIdx.x;
  if (i >= VV * 768) return;
  int v = i / 768, row = i - v * 768;
  float a = dbih[row];
#pragma unroll
  for (int e = 0; e < 8; ++e) a += dWih0[row * 8 + e] * emb[v * 8 + e];
  gi0[i] = a;
}

// ---- quarter matvec: 3 rows (row0,+256,+512), k-slice seg*32..+32, batched --
static __device__ __forceinline__ void mv3q(const f16* __restrict__ W, int row0, int seg,
                                            const f16* __restrict__ hsh,
                                            float& g0, float& g1, float& g2) {
  const uint4* w0 = (const uint4*)(W + (size_t)row0 * 256 + seg * 32);
  const uint4* w1 = (const uint4*)(W + ((size_t)row0 + 256) * 256 + seg * 32);
  const uint4* w2 = (const uint4*)(W + ((size_t)row0 + 512) * 256 + seg * 32);
  const uint4* hv = (const uint4*)(hsh + seg * 32);
  uint4 aq[4], bq[4], cq[4], hq[4];
#pragma unroll
  for (int j = 0; j < 4; ++j) {
    aq[j] = w0[j]; bq[j] = w1[j]; cq[j] = w2[j]; hq[j] = hv[j];
  }
#pragma unroll
  for (int j = 0; j < 4; ++j) {
    g0 = fdot2u(aq[j].x, hq[j].x, g0); g0 = fdot2u(aq[j].y, hq[j].y, g0);
    g0 = fdot2u(aq[j].z, hq[j].z, g0); g0 = fdot2u(aq[j].w, hq[j].w, g0);
    g1 = fdot2u(bq[j].x, hq[j].x, g1); g1 = fdot2u(bq[j].y, hq[j].y, g1);
    g1 = fdot2u(bq[j].z, hq[j].z, g1); g1 = fdot2u(bq[j].w, hq[j].w, g1);
    g2 = fdot2u(cq[j].x, hq[j].x, g2); g2 = fdot2u(cq[j].y, hq[j].y, g2);
    g2 = fdot2u(cq[j].z, hq[j].z, g2); g2 = fdot2u(cq[j].w, hq[j].w, g2);
  }
}
// half-row dot (128 elems at koff) of one W row vs LDS h
static __device__ __forceinline__ float mv1h(const f16* __restrict__ W, int koff,
                                             const f16* __restrict__ hsh) {
  const uint4* w = (const uint4*)(W + koff);
  const uint4* hv = (const uint4*)(hsh + koff);
  float g0 = 0.f, g1 = 0.f;
#pragma unroll
  for (int kc = 0; kc < 2; ++kc) {
    uint4 aq[8], hq[8];
#pragma unroll
    for (int j = 0; j < 8; ++j) { aq[j] = w[8 * kc + j]; hq[j] = hv[8 * kc + j]; }
#pragma unroll
    for (int j = 0; j < 8; j += 2) {
      g0 = fdot2u(aq[j].x, hq[j].x, g0); g0 = fdot2u(aq[j].y, hq[j].y, g0);
      g0 = fdot2u(aq[j].z, hq[j].z, g0); g0 = fdot2u(aq[j].w, hq[j].w, g0);
      g1 = fdot2u(aq[j+1].x, hq[j+1].x, g1); g1 = fdot2u(aq[j+1].y, hq[j+1].y, g1);
      g1 = fdot2u(aq[j+1].z, hq[j+1].z, g1); g1 = fdot2u(aq[j+1].w, hq[j+1].w, g1);
    }
  }
  return g0 + g1;
}

// ---------------- decoder LDS layout (dynamic, ~76 KB -> 2 WG/CU) ------------
#define SM_ENC    0        // 128 rows x 512 B (XOR-swizzled)
#define SM_ENCO   65536    // encOT: [32][128] f16 (rows 0..28 = outW@enc)
#define SM_SC     73728    // 128 f32 local scores / exp weights
#define SM_H0     74240    // f16[2][256]
#define SM_H1     75264    // f16[2][256]
#define SM_Q      76288    // f16[256]
#define SM_RED    76800    // f32[8]
#define SM_RED2   76832    // f32[8]
#define SM_CTXO   76864    // f32[4][32] gathered encO partials + (m,l)
#define SM_LG     77376    // f32[32]
#define SM_TOTAL  77568

// ------ persistent decoder: 4 WGs per batch (quarter-split), 2 WG/CU ---------
// R7 protocol with ~40% fewer atomic ops: own-quarter values written to LDS
// locally (poll only 3 partner quarters), q recomputed redundantly (no
// exchange round). 2 h-exchange rounds + 1 ctx round per step.
__global__ __launch_bounds__(512, 4)
void k_decoder(const f16* __restrict__ dwhh,   // (2,768,256)
               const f16* __restrict__ dwih1,  // (768,256)
               const f16* __restrict__ qw,     // (256,256)
               const f16* __restrict__ outw,   // (29,256)
               const f16* __restrict__ enc,    // (B,512,256)
               const f16* __restrict__ encO,   // (B,512,64): outWpad @ enc
               const float* __restrict__ gi0,  // (29,768)
               const float* __restrict__ dbih, // (2,768)
               const float* __restrict__ dbhh, // (2,768)
               const float* __restrict__ qb, const float* __restrict__ outb,
               const float* __restrict__ hs0, const float* __restrict__ hs1,
               const int* __restrict__ tseq,
               u64* __restrict__ xh0,          // (B,128) f16-pair packets
               u64* __restrict__ xh1,          // (B,128)
               u64* __restrict__ xcm,          // (B,4,32): 0..28 partials, 29=m, 30=l
               float* __restrict__ out)
{
  extern __shared__ __align__(16) char smem[];
  f16* encOT = (f16*)(smem + SM_ENCO);               // [32][128]
  float* sc   = (float*)(smem + SM_SC);
  f16 (*h0buf)[256] = (f16(*)[256])(smem + SM_H0);
  f16 (*h1buf)[256] = (f16(*)[256])(smem + SM_H1);
  f16* qsh  = (f16*)(smem + SM_Q);
  float* red  = (float*)(smem + SM_RED);
  float* red2 = (float*)(smem + SM_RED2);
  float (*ctxO)[32] = (float(*)[32])(smem + SM_CTXO);
  float* lg  = (float*)(smem + SM_LG);

  const int tid = threadIdx.x;
  const int wq = blockIdx.x >> 7, b = blockIdx.x & 127;
  const int o8 = tid >> 3, seg = tid & 7, gout = wq * 64 + o8;
  const int pair = tid >> 1, half = tid & 1, koff = half * 128;
  const f16* dwhh1 = dwhh + (size_t)768 * 256;

  u64* bxh0 = xh0 + (size_t)b * 128;
  u64* bxh1 = xh1 + (size_t)b * 128;
  u64* bxcm = xcm + (size_t)b * 4 * 32;

  // hoisted constants (per owner row gout)
  const float bh00 = dbhh[gout], bh01 = dbhh[gout + 256], bh02 = dbhh[gout + 512];
  const float bi10 = dbih[768 + gout], bi11 = dbih[768 + gout + 256], bi12 = dbih[768 + gout + 512];
  const float bh10 = dbhh[768 + gout], bh11 = dbhh[768 + gout + 256], bh12 = dbhh[768 + gout + 512];
  const float qb2 = qb[pair];
  float h0own = hs0[b * 256 + gout] + hs0[32768 + b * 256 + gout];
  float h1own = hs1[b * 256 + gout] + hs1[32768 + b * 256 + gout];
  // logits weights in registers
  const int lv_ = tid >> 4, lk_ = tid & 15;
  uint4 ow0 = {0,0,0,0}, ow1 = {0,0,0,0}; float outbv = 0.f;
  if (tid < VV * 16) {
    const uint4* owp = (const uint4*)(outw + (size_t)lv_ * 256 + lk_ * 16);
    ow0 = owp[0]; ow1 = owp[1];
    outbv = outb[lv_];
  }
  if (tid < 256) {
    h0buf[0][tid] = (f16)(hs0[b * 256 + tid] + hs0[32768 + b * 256 + tid]);
    h1buf[0][tid] = (f16)(hs1[b * 256 + tid] + hs1[32768 + b * 256 + tid]);
  }
  // fill enc quarter: global rows [wq*128,+128), XOR-swizzled 16B segs
  {
    const int r = tid >> 2, q8 = tid & 3;
    const uint4* src = (const uint4*)(enc + ((size_t)b * 512 + wq * 128 + r) * 256) + q8 * 8;
    const int sw = (r & 31) << 4;
#pragma unroll
    for (int j = 0; j < 8; ++j) {
      uint4 v = src[j];
      *(uint4*)(smem + r * 512 + (((q8 * 8 + j) * 16) ^ sw)) = v;
    }
  }
  // fill encOT: transpose encO rows [wq*128,+128) cols [0,32) -> [32][128]
  {
    const int r = tid >> 2, g = tid & 3;
    if (g < 2) {
      const uint4* src = (const uint4*)(encO + ((size_t)b * 512 + wq * 128 + r) * 64 + g * 16);
#pragma unroll
      for (int u = 0; u < 2; ++u) {
        uint4 v = src[u];
        const f16* vp = (const f16*)&v;
#pragma unroll
        for (int j = 0; j < 8; ++j) encOT[(g * 16 + u * 8 + j) * 128 + r] = vp[j];
      }
    }
  }
  int tok = tseq[b * 64];
  __syncthreads();

  for (int s = 0; s < NSTEP; ++s) {
    const int cur = s & 1, nxt = cur ^ 1;
    const unsigned tag = (unsigned)(s + 1);

    // ---- P1 cell0: quarter gate rows; pub packets; own quarter -> LDS ----
    {
      float g0 = 0.f, g1 = 0.f, g2 = 0.f;
      mv3q(dwhh, gout, seg, h0buf[cur], g0, g1, g2);
      g0 += __shfl_xor(g0, 1); g0 += __shfl_xor(g0, 2); g0 += __shfl_xor(g0, 4);
      g1 += __shfl_xor(g1, 1); g1 += __shfl_xor(g1, 2); g1 += __shfl_xor(g1, 4);
      g2 += __shfl_xor(g2, 1); g2 += __shfl_xor(g2, 2); g2 += __shfl_xor(g2, 4);
      if (seg == 0) {
        const float* giP = gi0 + tok * 768;
        float r = sigm_(giP[gout] + g0 + bh00);
        float z = sigm_(giP[gout + 256] + g1 + bh01);
        float n = tanhf(giP[gout + 512] + r * (g2 + bh02));
        h0own = (1.f - z) * n + z * h0own;
      }
      float pnext = __shfl_down(h0own, 8);
      if (seg == 0) {
        h0buf[nxt][gout] = (f16)h0own;       // own quarter -> LDS directly
        if (!(o8 & 1))
          pubp(bxh0 + (gout >> 1), tag, pack2h(h0own, pnext));
      }
    }
    if (tid < 128 && (tid >> 5) != wq)       // poll partner quarters only
      ((uint32_t*)h0buf[nxt])[tid] = pollp(bxh0 + tid, tag);
    __syncthreads();             // B1: h0' gathered

    // ---- P2 cell1: quarter gate rows; pub packets; own quarter -> LDS ----
    {
      float a0 = 0.f, a1 = 0.f, a2 = 0.f;
      mv3q(dwih1, gout, seg, h0buf[nxt], a0, a1, a2);
      float c0 = 0.f, c1 = 0.f, c2 = 0.f;
      mv3q(dwhh1, gout, seg, h1buf[cur], c0, c1, c2);
      a0 += __shfl_xor(a0, 1); a0 += __shfl_xor(a0, 2); a0 += __shfl_xor(a0, 4);
      a1 += __shfl_xor(a1, 1); a1 += __shfl_xor(a1, 2); a1 += __shfl_xor(a1, 4);
      a2 += __shfl_xor(a2, 1); a2 += __shfl_xor(a2, 2); a2 += __shfl_xor(a2, 4);
      c0 += __shfl_xor(c0, 1); c0 += __shfl_xor(c0, 2); c0 += __shfl_xor(c0, 4);
      c1 += __shfl_xor(c1, 1); c1 += __shfl_xor(c1, 2); c1 += __shfl_xor(c1, 4);
      c2 += __shfl_xor(c2, 1); c2 += __shfl_xor(c2, 2); c2 += __shfl_xor(c2, 4);
      if (seg == 0) {
        float r = sigm_(a0 + bi10 + c0 + bh10);
        float z = sigm_(a1 + bi11 + c1 + bh11);
        float n = tanhf(a2 + bi12 + r * (c2 + bh12));
        h1own = (1.f - z) * n + z * h1own;
      }
      float pnext = __shfl_down(h1own, 8);
      if (seg == 0) {
        h1buf[nxt][gout] = (f16)h1own;       // own quarter -> LDS directly
        if (!(o8 & 1))
          pubp(bxh1 + (gout >> 1), tag, pack2h(h1own, pnext));
      }
    }
    if (tid < 128 && (tid >> 5) != wq)
      ((uint32_t*)h1buf[nxt])[tid] = pollp(bxh1 + tid, tag);
    __syncthreads();             // B2: h1' gathered

    // ---- P3 q: full, redundant (qw L2-resident; no exchange round) ----
    {
      float qv = mv1h(qw + (size_t)pair * 256, koff, h1buf[nxt]);
      qv += __shfl_xor(qv, 1);
      if (half == 0) qsh[pair] = (f16)(qv + qb2);
    }
    __syncthreads();             // B3: qsh ready

    // ---- P4 scores over MY 128 LDS enc rows (local only) ----
    {
      const int r = tid >> 2, sg = tid & 3;
      const int sw = (r & 31) << 4;
      const uint4* q4 = (const uint4*)qsh;
      float s0 = 0.f, s1 = 0.f;
#pragma unroll
      for (int j = 0; j < 8; ++j) {
        int sgi = sg * 8 + j;
        uint4 ev = *(const uint4*)(smem + r * 512 + ((sgi * 16) ^ sw));
        uint4 qv = q4[sgi];
        s0 = fdot2u(ev.x, qv.x, s0); s0 = fdot2u(ev.y, qv.y, s0);
        s1 = fdot2u(ev.z, qv.z, s1); s1 = fdot2u(ev.w, qv.w, s1);
      }
      float sv = s0 + s1;
      sv += __shfl_xor(sv, 1); sv += __shfl_xor(sv, 2);
      if (sg == 0) sc[r] = sv;
    }
    __syncthreads();             // B4: sc ready

    // ---- local softmax stats ----
    float vdup = sc[tid & 127];
    float mloc = vdup;
#pragma unroll
    for (int off = 32; off; off >>= 1) mloc = fmaxf(mloc, __shfl_xor(mloc, off));
    if ((tid & 63) == 0) red[tid >> 6] = mloc;
    __syncthreads();             // B5
    float m_w = red[0];
#pragma unroll
    for (int wv = 1; wv < 8; ++wv) m_w = fmaxf(m_w, red[wv]);
    float e = 0.f;
    if (tid < 128) { e = __expf(sc[tid] - m_w); sc[tid] = e; }
    float ls = e;
#pragma unroll
    for (int off = 32; off; off >>= 1) ls += __shfl_xor(ls, off);
    if ((tid & 63) == 0) red2[tid >> 6] = ls;
    __syncthreads();             // B6: sc=exp ready + red2
    float l_w = red2[0] + red2[1] + red2[2] + red2[3]
              + red2[4] + red2[5] + red2[6] + red2[7];

    // ---- P5 weighted-encO partials (29) + (m,l); own quarter -> LDS ----
    {
      const int oo = tid >> 4, tk = tid & 15;
      if (oo < VV) {
        uint4 ev = *(const uint4*)(encOT + oo * 128 + tk * 8);
        const f16* ep = (const f16*)&ev;
        const float* wp = sc + tk * 8;
        float a = 0.f;
#pragma unroll
        for (int j = 0; j < 8; ++j) a += wp[j] * (float)ep[j];
        a += __shfl_xor(a, 1); a += __shfl_xor(a, 2);
        a += __shfl_xor(a, 4); a += __shfl_xor(a, 8);
        if (tk == 0) {
          ctxO[wq][oo] = a;                   // own quarter -> LDS directly
          pubf(bxcm + wq * 32 + oo, tag, a);
        }
      }
      if (tid == 480) { ctxO[wq][29] = m_w; pubf(bxcm + wq * 32 + 29, tag, m_w); }
      if (tid == 481) { ctxO[wq][30] = l_w; pubf(bxcm + wq * 32 + 30, tag, l_w); }
    }
    if (tid < 128 && (tid >> 5) != wq) {     // poll partner quarters only
      const int q4 = tid >> 5, ix = tid & 31;
      if (ix < 31) ctxO[q4][ix] = pollf(bxcm + q4 * 32 + ix, tag);
    }
    __syncthreads();             // B7: ctxO gathered

    // ---- P6 logits = outW@h1' + ctx-part + outb ----
    if (tid < VV * 16) {
      const uint32_t* h1u = (const uint32_t*)h1buf[nxt] + lk_ * 8;
      float acc = 0.f;
      acc = fdot2u(ow0.x, h1u[0], acc); acc = fdot2u(ow0.y, h1u[1], acc);
      acc = fdot2u(ow0.z, h1u[2], acc); acc = fdot2u(ow0.w, h1u[3], acc);
      acc = fdot2u(ow1.x, h1u[4], acc); acc = fdot2u(ow1.y, h1u[5], acc);
      acc = fdot2u(ow1.z, h1u[6], acc); acc = fdot2u(ow1.w, h1u[7], acc);
      acc += __shfl_xor(acc, 1); acc += __shfl_xor(acc, 2);
      acc += __shfl_xor(acc, 4); acc += __shfl_xor(acc, 8);
      if (lk_ == 0) {
        float m0 = ctxO[0][29], m1 = ctxO[1][29], m2 = ctxO[2][29], m3 = ctxO[3][29];
        float m = fmaxf(fmaxf(m0, m1), fmaxf(m2, m3));
        float w0 = __expf(m0 - m), w1 = __expf(m1 - m);
        float w2 = __expf(m2 - m), w3 = __expf(m3 - m);
        float l = ctxO[0][30] * w0 + ctxO[1][30] * w1
                + ctxO[2][30] * w2 + ctxO[3][30] * w3;
        float cs = ctxO[0][lv_] * w0 + ctxO[1][lv_] * w1
                 + ctxO[2][lv_] * w2 + ctxO[3][lv_] * w3;
        float lvv = acc + cs / l + outbv;
        lg[lv_] = lvv;
        if (wq == 0) out[((size_t)b * NSTEP + s) * VV + lv_] = lvv;
      }
    }
    __syncthreads();             // B8: lg ready

    // ---- argmax (identical in every WG) ----
    {
      const int lane = tid & 63;
      float val = (lane < VV) ? lg[lane] : -3.4e38f;
      int bi = lane;
#pragma unroll
      for (int off = 32; off; off >>= 1) {
        float ov = __shfl_xor(val, off);
        int oi = __shfl_xor(bi, off);
        if (ov > val || (ov == val && oi < bi)) { val = ov; bi = oi; }
      }
      tok = bi;
    }
  }

  // final hidden
  if (wq == 0 && tid < 256) {
    out[233856 + b * 256 + tid] = (float)h0buf[NSTEP & 1][tid];
    out[233856 + 32768 + b * 256 + tid] = (float)h1buf[NSTEP & 1][tid];
  }
}

extern "C" void kernel_launch(void* const* d_in, const int* in_sizes, int n_in,
                              void* d_out, int out_size, void* d_ws, size_t ws_size,
                              hipStream_t stream) {
  (void)in_sizes; (void)n_in; (void)out_size; (void)ws_size;
  const float* x     = (const float*)d_in[0];
  const int*   tseq  = (const int*)d_in[1];
  const float* eWih0 = (const float*)d_in[2];
  const float* eWhh0 = (const float*)d_in[3];
  const float* ebih0 = (const float*)d_in[4];
  const float* ebhh0 = (const float*)d_in[5];
  const float* eWih1 = (const float*)d_in[6];
  const float* eWhh1 = (const float*)d_in[7];
  const float* ebih1 = (const float*)d_in[8];
  const float* ebhh1 = (const float*)d_in[9];
  const float* e2dW  = (const float*)d_in[10];
  const float* e2db  = (const float*)d_in[11];
  const float* dWih0 = (const float*)d_in[12];
  const float* dWih1 = (const float*)d_in[13];
  const float* dWhh  = (const float*)d_in[14];
  const float* dbih  = (const float*)d_in[15];
  const float* dbhh  = (const float*)d_in[16];
  const float* qW    = (const float*)d_in[17];
  const float* qb    = (const float*)d_in[18];
  const float* outW  = (const float*)d_in[19];
  const float* outb  = (const float*)d_in[20];
  const float* emb   = (const float*)d_in[21];

  // ---- workspace ledger ----
  uint8_t* ws = (uint8_t*)d_ws;
  size_t o = 0;
  auto take = [&](size_t bytes) -> void* {
    void* p = ws + o;
    o += (bytes + 255) & ~(size_t)255;
    return p;
  };
  f16* whh0_16  = (f16*)take((size_t)2 * 768 * 256 * 2);
  f16* whh1_16  = (f16*)take((size_t)2 * 768 * 256 * 2);
  f16* wih1_16  = (f16*)take((size_t)2 * 768 * 512 * 2);
  f16* e2d_16   = (f16*)take((size_t)256 * 512 * 2);
  f16* qw_16    = (f16*)take((size_t)256 * 256 * 2);
  f16* outw_16  = (f16*)take((size_t)29 * 256 * 2);
  f16* owpad_16 = (f16*)take((size_t)64 * 256 * 2);     // outW zero-padded to 64 rows
  f16* dwih1_16 = (f16*)take((size_t)768 * 256 * 2);
  f16* dwhh_16  = (f16*)take((size_t)2 * 768 * 256 * 2);
  f16* y0   = (f16*)take((size_t)BT * 512 * 2);          // enc aliases later
  f16* y1   = (f16*)take((size_t)BT * 512 * 2);
  f16* gi   = (f16*)take((size_t)BB * CHUNK * 1536 * 2); // encO aliases later
  float* hs0 = (float*)take((size_t)2 * BB * 256 * 4);
  float* hs1 = (float*)take((size_t)2 * BB * 256 * 4);
  float* gi0 = (float*)take((size_t)VV * 768 * 4);
  u64* xh0  = (u64*)take((size_t)BB * 128 * 8);
  u64* xh1  = (u64*)take((size_t)BB * 128 * 8);
  u64* xcm  = (u64*)take((size_t)BB * 4 * 32 * 8);
  f16* enc  = y0;  // alias: y0 dead after last gi chunk GEMM
  f16* encO = (f16*)gi;  // alias: gi dead after last k_scan<1>

  hipMemsetAsync(hs0, 0, (size_t)2 * BB * 256 * 4, stream);
  hipMemsetAsync(hs1, 0, (size_t)2 * BB * 256 * 4, stream);
  hipMemsetAsync(xh0, 0, (size_t)BB * 128 * 8, stream);
  hipMemsetAsync(xh1, 0, (size_t)BB * 128 * 8, stream);
  hipMemsetAsync(xcm, 0, (size_t)BB * 4 * 32 * 8, stream);
  hipMemsetAsync(owpad_16, 0, (size_t)64 * 256 * 2, stream);

  auto cvt = [&](const float* s, f16* d, int n) {
    k_cvt<<<(n + 255) / 256, 256, 0, stream>>>(s, d, n);
  };
  cvt(eWhh0, whh0_16, 2 * 768 * 256);
  cvt(eWhh1, whh1_16, 2 * 768 * 256);
  cvt(eWih1, wih1_16, 2 * 768 * 512);
  cvt(e2dW,  e2d_16,  256 * 512);
  cvt(qW,    qw_16,   256 * 256);
  cvt(outW,  outw_16, 29 * 256);
  cvt(outW,  owpad_16, 29 * 256);
  cvt(dWih1, dwih1_16, 768 * 256);
  cvt(dWhh,  dwhh_16, 2 * 768 * 256);
  k_gi0<<<(VV * 768 + 255) / 256, 256, 0, stream>>>(dWih0, dbih, emb, gi0);

  // encoder layer 0
  k_scan<0><<<256, 512, 0, stream>>>(x, nullptr, (const uint32_t*)whh0_16,
                                     eWih0, ebih0, ebhh0, y0, hs0, 0, TT);

  // encoder layer 1: time-chunked gi GEMM + scan
  const long BSTR = (long)TT * 512;
  for (int c = 0; c < TT / CHUNK; ++c) {
    const int t0 = c * CHUNK;
    k_gemm<<<dim3(BB * CHUNK / 64, 12), 256, 0, stream>>>(
        y0 + (size_t)t0 * 512, wih1_16, gi, ebih1,
        512, 6, BSTR, 512, 1536, 0);
    k_gemm<<<dim3(BB * CHUNK / 64, 12), 256, 0, stream>>>(
        y0 + (size_t)(TT - 1 - t0) * 512, wih1_16 + (size_t)768 * 512, gi, ebih1 + 768,
        512, 6, BSTR, -512, 1536, 768);
    k_scan<1><<<256, 512, 0, stream>>>(nullptr, gi, (const uint32_t*)whh1_16,
                                       nullptr, nullptr, ebhh1, y1, hs1, t0, CHUNK);
  }

  // enc = y1 @ e2d^T + b   (writes into y0's region)
  k_gemm<<<dim3(BT / 64, 4), 256, 0, stream>>>(y1, e2d_16, enc, e2db,
                                               512, 30, 0, 512, 256, 0);

  // encO = enc @ outWpad^T  (BT x 64, f16)  — writes into gi's region
  k_gemm<<<dim3(BT / 64, 1), 256, 0, stream>>>(enc, owpad_16, encO, nullptr,
                                               256, 30, 0, 256, 64, 0);

  // persistent decoder: 4 WGs per batch, 512 WGs = 2 per CU
  hipFuncSetAttribute((const void*)k_decoder,
                      hipFuncAttributeMaxDynamicSharedMemorySize, SM_TOTAL);
  k_decoder<<<GQ * BB, 512, SM_TOTAL, stream>>>(dwhh_16, dwih1_16, qw_16, outw_16,
                                                enc, encO, gi0, dbih, dbhh, qb, outb,
                                                hs0, hs1, tseq,
                                                xh0, xh1, xcm,
                                                (float*)d_out);
}

// Round 13
// 4574.742 us; speedup vs baseline: 1.0617x; 1.0617x over previous
//
#include <hip/hip_runtime.h>
#include <hip/hip_bf16.h>
#include <hip/hip_fp16.h>
#include <stdint.h>

// Problem dims
#define BB 128
#define TT 512
#define HH 256
#define VV 29
#define NSTEP 63
#define BT (BB*TT)
#define CHUNK 64   // layer-1 time chunk
#define GQ 4       // decoder WGs per batch

typedef _Float16 f16;
typedef _Float16 f16x2 __attribute__((ext_vector_type(2)));
typedef _Float16 f16x8 __attribute__((ext_vector_type(8)));
typedef float f32x4 __attribute__((ext_vector_type(4)));
typedef unsigned long long u64;

static __device__ __forceinline__ float fdot2u(uint32_t a, uint32_t b, float c) {
  return __builtin_amdgcn_fdot2(__builtin_bit_cast(f16x2, a),
                                __builtin_bit_cast(f16x2, b), c, false);
}
static __device__ __forceinline__ float sigm_(float x) {
  return 1.0f / (1.0f + __expf(-x));
}
// tagged exchange: (tag<<32)|payload32 in one relaxed agent-scope atomic.
// PUBLISH VIA ATOMIC STORE (not exchange): R5 measured FETCH~0 with stores;
// R6's switch to RMW-exchange coincided with FETCH 0.13->5.95 GB (L2 poison
// hypothesis). Poll with s_sleep backoff.
static __device__ __forceinline__ void pubp(u64* p, unsigned tag, uint32_t pay) {
  u64 pkt = ((u64)tag << 32) | (u64)pay;
  __hip_atomic_store(p, pkt, __ATOMIC_RELAXED, __HIP_MEMORY_SCOPE_AGENT);
}
static __device__ __forceinline__ uint32_t pollp(const u64* p, unsigned tag) {
  u64 pkt = __hip_atomic_load(p, __ATOMIC_RELAXED, __HIP_MEMORY_SCOPE_AGENT);
  while ((unsigned)(pkt >> 32) < tag) {
    __builtin_amdgcn_s_sleep(8);
    pkt = __hip_atomic_load(p, __ATOMIC_RELAXED, __HIP_MEMORY_SCOPE_AGENT);
  }
  return (uint32_t)pkt;
}
static __device__ __forceinline__ void pubf(u64* p, unsigned tag, float v) {
  pubp(p, tag, __builtin_bit_cast(uint32_t, v));
}
static __device__ __forceinline__ float pollf(const u64* p, unsigned tag) {
  return __builtin_bit_cast(float, pollp(p, tag));
}
static __device__ __forceinline__ uint32_t pack2h(float a, float b) {
  unsigned short ua = __builtin_bit_cast(unsigned short, (f16)a);
  unsigned short ub = __builtin_bit_cast(unsigned short, (f16)b);
  return (uint32_t)ua | ((uint32_t)ub << 16);
}

// ---------------- fp32 -> f16 convert ----------------
__global__ void k_cvt(const float* __restrict__ s, f16* __restrict__ d, int n) {
  int i = blockIdx.x * 256 + threadIdx.x;
  if (i < n) d[i] = (f16)s[i];
}

// ---------------- persistent GRU scan: 1 WG per (batch, dir) ----------------
// h double-buffered in LDS -> ONE barrier per step.
template<int LAYER>
__global__ __launch_bounds__(512, 2)
void k_scan(const float* __restrict__ x,        // L0: (B,T,2)
            const f16* __restrict__ gi,         // L1: (B,nsteps,1536) chunk-local
            const uint32_t* __restrict__ whh,   // (2,768,128) as half2
            const float* __restrict__ wih0,     // L0: (2,768,2)
            const float* __restrict__ bih,      // L0: (2,768)
            const float* __restrict__ bhh,      // (2,768)
            f16* __restrict__ y,                // (B,T,512) [t][dir*256+p]
            float* __restrict__ hstate,         // (2,B,256) f32
            int t0, int nsteps)
{
  const int wg = blockIdx.x, b = wg >> 1, dir = wg & 1;
  const int tid = threadIdx.x, pair = tid >> 1, half = tid & 1;
  __shared__ __align__(16) uint4 hv4[2][32];   // h as f16[256], double-buffered

  uint4 w0[16], w1[16], w2[16];
  {
    const uint32_t* wp = whh + (size_t)dir * 768 * 128;
    const uint4* r0 = (const uint4*)(wp + (size_t)pair * 128 + half * 64);
    const uint4* r1 = (const uint4*)(wp + (size_t)(pair + 256) * 128 + half * 64);
    const uint4* r2 = (const uint4*)(wp + (size_t)(pair + 512) * 128 + half * 64);
#pragma unroll
    for (int i = 0; i < 16; i++) { w0[i] = r0[i]; w1[i] = r1[i]; w2[i] = r2[i]; }
  }
  const float bh0 = bhh[dir * 768 + pair];
  const float bh1 = bhh[dir * 768 + pair + 256];
  const float bh2 = bhh[dir * 768 + pair + 512];
  float bi0 = 0, bi1 = 0, bi2 = 0;
  float wi00 = 0, wi01 = 0, wi10 = 0, wi11 = 0, wi20 = 0, wi21 = 0;
  if (LAYER == 0) {
    bi0 = bih[dir * 768 + pair];
    bi1 = bih[dir * 768 + pair + 256];
    bi2 = bih[dir * 768 + pair + 512];
    wi00 = wih0[(dir * 768 + pair) * 2 + 0];
    wi01 = wih0[(dir * 768 + pair) * 2 + 1];
    wi10 = wih0[(dir * 768 + pair + 256) * 2 + 0];
    wi11 = wih0[(dir * 768 + pair + 256) * 2 + 1];
    wi20 = wih0[(dir * 768 + pair + 512) * 2 + 0];
    wi21 = wih0[(dir * 768 + pair + 512) * 2 + 1];
  }
  float* hs = hstate + ((size_t)dir * BB + b) * 256;
  float hreg = hs[pair];
  if (tid < 128) {
    f16x2 p2; p2[0] = (f16)hs[2 * tid]; p2[1] = (f16)hs[2 * tid + 1];
    ((uint32_t*)hv4[0])[tid] = __builtin_bit_cast(uint32_t, p2);
  }
  __syncthreads();

  int cb = 0;
  for (int s = 0; s < nsteps; ++s) {
    const int t = dir ? (TT - 1 - t0 - s) : (t0 + s);
    float gr, gz, gn;
    if (LAYER == 0) {
      float x0 = x[((size_t)b * TT + t) * 2 + 0];
      float x1 = x[((size_t)b * TT + t) * 2 + 1];
      gr = wi00 * x0 + wi01 * x1 + bi0;
      gz = wi10 * x0 + wi11 * x1 + bi1;
      gn = wi20 * x0 + wi21 * x1 + bi2;
    } else {
      const f16* g = gi + ((size_t)b * nsteps + s) * 1536 + dir * 768 + pair;
      gr = (float)g[0]; gz = (float)g[256]; gn = (float)g[512];
    }
    const uint4* hw = hv4[cb] + half * 16;
    float a0 = 0.f, a1 = 0.f, a2 = 0.f;
#pragma unroll
    for (int j = 0; j < 16; ++j) {
      uint4 hh = hw[j];
      a0 = fdot2u(w0[j].x, hh.x, a0); a0 = fdot2u(w0[j].y, hh.y, a0);
      a0 = fdot2u(w0[j].z, hh.z, a0); a0 = fdot2u(w0[j].w, hh.w, a0);
      a1 = fdot2u(w1[j].x, hh.x, a1); a1 = fdot2u(w1[j].y, hh.y, a1);
      a1 = fdot2u(w1[j].z, hh.z, a1); a1 = fdot2u(w1[j].w, hh.w, a1);
      a2 = fdot2u(w2[j].x, hh.x, a2); a2 = fdot2u(w2[j].y, hh.y, a2);
      a2 = fdot2u(w2[j].z, hh.z, a2); a2 = fdot2u(w2[j].w, hh.w, a2);
    }
    a0 += __shfl_xor(a0, 1);
    a1 += __shfl_xor(a1, 1);
    a2 += __shfl_xor(a2, 1);

    float r = sigm_(gr + a0 + bh0);
    float z = sigm_(gz + a1 + bh1);
    float n = tanhf(gn + r * (a2 + bh2));
    float hn = (1.0f - z) * n + z * hreg;
    hreg = hn;
    if (half == 0) {
      y[((size_t)b * TT + t) * 512 + dir * 256 + pair] = (f16)hn;
      ((f16*)hv4[cb ^ 1])[pair] = (f16)hn;   // write OTHER buffer
    }
    __syncthreads();  // nxt buffer complete; cur reads all done (pre-barrier)
    cb ^= 1;
  }
  if (half == 0) hs[pair] = hreg;
}

// ---------------- f16 MFMA GEMM: C = Arows @ Bt^T + bias ---------------------
__global__ __launch_bounds__(256)
void k_gemm(const f16* __restrict__ A, const f16* __restrict__ Bt,
            f16* __restrict__ C, const float* __restrict__ bias,
            int K, int shift, long bstride, int inner, int ldc, int coloff)
{
  const int m0 = blockIdx.x * 64, n0 = blockIdx.y * 64;
  const int tid = threadIdx.x, lane = tid & 63, wv = tid >> 6;
  __shared__ __align__(16) f16 As[64 * 40];
  __shared__ __align__(16) f16 Bs[64 * 40];
  f32x4 acc[4] = {{0,0,0,0},{0,0,0,0},{0,0,0,0},{0,0,0,0}};
  const int lrow = tid >> 2, lseg = tid & 3;
  const int ml = lane & 15, quad = lane >> 4;
  const int r = m0 + lrow;
  const f16* arow = A + (long)(r >> shift) * bstride
                      + (long)(r & ((1 << shift) - 1)) * inner;
  const f16* brow = Bt + (size_t)(n0 + lrow) * K;
  for (int k0 = 0; k0 < K; k0 += 32) {
    uint4 av = *(const uint4*)(arow + k0 + lseg * 8);
    uint4 bv = *(const uint4*)(brow + k0 + lseg * 8);
    __syncthreads();
    *(uint4*)(As + lrow * 40 + lseg * 8) = av;
    *(uint4*)(Bs + lrow * 40 + lseg * 8) = bv;
    __syncthreads();
    f16x8 af = *(const f16x8*)(As + (wv * 16 + ml) * 40 + quad * 8);
#pragma unroll
    for (int ns = 0; ns < 4; ++ns) {
      f16x8 bf = *(const f16x8*)(Bs + (ns * 16 + ml) * 40 + quad * 8);
      acc[ns] = __builtin_amdgcn_mfma_f32_16x16x32_f16(af, bf, acc[ns], 0, 0, 0);
    }
  }
#pragma unroll
  for (int ns = 0; ns < 4; ++ns) {
#pragma unroll
    for (int rr = 0; rr < 4; ++rr) {
      int row = m0 + wv * 16 + quad * 4 + rr;
      int col = n0 + ns * 16 + ml;
      float v = acc[ns][rr];
      if (bias) v += bias[col];
      C[(size_t)row * ldc + coloff + col] = (f16)v;
    }
  }
}

// ---------------- gi0[v][row] = dWih0 @ emb[v] + dbih  (29 x 768, f32) -------
__global__ void k_gi0(const float* __restrict__ dWih0, const float* __restrict__ dbih,
                      const float* __restrict__ emb, float* __restrict__ gi0) {
  int i = blockIdx.x * 256 + threadIdx.x;
  if (i >= VV * 768) return;
  int v = i / 768, row = i - v * 768;
  float a = dbih[row];
#pragma unroll
  for (int e = 0; e < 8; ++e) a += dWih0[row * 8 + e] * emb[v * 8 + e];
  gi0[i] = a;
}

// ---- quarter matvec: 3 rows (row0,+256,+512), k-slice seg*32..+32, batched --
static __device__ __forceinline__ void mv3q(const f16* __restrict__ W, int row0, int seg,
                                            const f16* __restrict__ hsh,
                                            float& g0, float& g1, float& g2) {
  const uint4* w0 = (const uint4*)(W + (size_t)row0 * 256 + seg * 32);
  const uint4* w1 = (const uint4*)(W + ((size_t)row0 + 256) * 256 + seg * 32);
  const uint4* w2 = (const uint4*)(W + ((size_t)row0 + 512) * 256 + seg * 32);
  const uint4* hv = (const uint4*)(hsh + seg * 32);
  uint4 aq[4], bq[4], cq[4], hq[4];
#pragma unroll
  for (int j = 0; j < 4; ++j) {
    aq[j] = w0[j]; bq[j] = w1[j]; cq[j] = w2[j]; hq[j] = hv[j];
  }
#pragma unroll
  for (int j = 0; j < 4; ++j) {
    g0 = fdot2u(aq[j].x, hq[j].x, g0); g0 = fdot2u(aq[j].y, hq[j].y, g0);
    g0 = fdot2u(aq[j].z, hq[j].z, g0); g0 = fdot2u(aq[j].w, hq[j].w, g0);
    g1 = fdot2u(bq[j].x, hq[j].x, g1); g1 = fdot2u(bq[j].y, hq[j].y, g1);
    g1 = fdot2u(bq[j].z, hq[j].z, g1); g1 = fdot2u(bq[j].w, hq[j].w, g1);
    g2 = fdot2u(cq[j].x, hq[j].x, g2); g2 = fdot2u(cq[j].y, hq[j].y, g2);
    g2 = fdot2u(cq[j].z, hq[j].z, g2); g2 = fdot2u(cq[j].w, hq[j].w, g2);
  }
}
// single row, k-slice seg*32..+32
static __device__ __forceinline__ float mv1q(const f16* __restrict__ W, int row, int seg,
                                             const f16* __restrict__ hsh) {
  const uint4* w = (const uint4*)(W + (size_t)row * 256 + seg * 32);
  const uint4* hv = (const uint4*)(hsh + seg * 32);
  uint4 aq[4], hq[4];
#pragma unroll
  for (int j = 0; j < 4; ++j) { aq[j] = w[j]; hq[j] = hv[j]; }
  float g = 0.f;
#pragma unroll
  for (int j = 0; j < 4; ++j) {
    g = fdot2u(aq[j].x, hq[j].x, g); g = fdot2u(aq[j].y, hq[j].y, g);
    g = fdot2u(aq[j].z, hq[j].z, g); g = fdot2u(aq[j].w, hq[j].w, g);
  }
  return g;
}

// ---------------- decoder LDS layout (dynamic, ~76 KB -> 2 WG/CU) ------------
#define SM_ENC    0        // 128 rows x 512 B (XOR-swizzled)
#define SM_ENCO   65536    // encOT: [32][128] f16 (rows 0..28 = outW@enc)
#define SM_SC     73728    // 128 f32 local scores / exp weights
#define SM_H0     74240    // f16[2][256]
#define SM_H1     75264    // f16[2][256]
#define SM_Q      76288    // f16[256]
#define SM_RED    76800    // f32[8]
#define SM_RED2   76832    // f32[8]
#define SM_CTXO   76864    // f32[4][32] gathered encO partials + (m,l)
#define SM_LG     77376    // f32[32]
#define SM_TOTAL  77568

// ------ persistent decoder: 4 WGs per batch (quarter-split), 2 WG/CU ---------
// R11 structure; pubs via atomic STORE (R5-style, L2-poison test); own-quarter
// values written to LDS directly (poll only 3 partner quarters). q exchange
// retained (quarter compute — R12 showed redundant q costs L2 misses).
__global__ __launch_bounds__(512, 4)
void k_decoder(const f16* __restrict__ dwhh,   // (2,768,256)
               const f16* __restrict__ dwih1,  // (768,256)
               const f16* __restrict__ qw,     // (256,256)
               const f16* __restrict__ outw,   // (29,256)
               const f16* __restrict__ enc,    // (B,512,256)
               const f16* __restrict__ encO,   // (B,512,64): outWpad @ enc
               const float* __restrict__ gi0,  // (29,768)
               const float* __restrict__ dbih, // (2,768)
               const float* __restrict__ dbhh, // (2,768)
               const float* __restrict__ qb, const float* __restrict__ outb,
               const float* __restrict__ hs0, const float* __restrict__ hs1,
               const int* __restrict__ tseq,
               u64* __restrict__ xh0,          // (B,128) f16-pair packets
               u64* __restrict__ xh1,          // (B,128)
               u64* __restrict__ xq,           // (B,128)
               u64* __restrict__ xcm,          // (B,4,32): 0..28 partials, 29=m, 30=l
               float* __restrict__ out)
{
  extern __shared__ __align__(16) char smem[];
  f16* encOT = (f16*)(smem + SM_ENCO);               // [32][128]
  float* sc   = (float*)(smem + SM_SC);
  f16 (*h0buf)[256] = (f16(*)[256])(smem + SM_H0);
  f16 (*h1buf)[256] = (f16(*)[256])(smem + SM_H1);
  f16* qsh  = (f16*)(smem + SM_Q);
  float* red  = (float*)(smem + SM_RED);
  float* red2 = (float*)(smem + SM_RED2);
  float (*ctxO)[32] = (float(*)[32])(smem + SM_CTXO);
  float* lg  = (float*)(smem + SM_LG);

  const int tid = threadIdx.x;
  const int wq = blockIdx.x >> 7, b = blockIdx.x & 127;
  const int o8 = tid >> 3, seg = tid & 7, gout = wq * 64 + o8;
  const f16* dwhh1 = dwhh + (size_t)768 * 256;

  u64* bxh0 = xh0 + (size_t)b * 128;
  u64* bxh1 = xh1 + (size_t)b * 128;
  u64* bxq  = xq  + (size_t)b * 128;
  u64* bxcm = xcm + (size_t)b * 4 * 32;

  // hoisted constants (per owner row gout)
  const float bh00 = dbhh[gout], bh01 = dbhh[gout + 256], bh02 = dbhh[gout + 512];
  const float bi10 = dbih[768 + gout], bi11 = dbih[768 + gout + 256], bi12 = dbih[768 + gout + 512];
  const float bh10 = dbhh[768 + gout], bh11 = dbhh[768 + gout + 256], bh12 = dbhh[768 + gout + 512];
  const float qbv = qb[gout];
  float h0own = hs0[b * 256 + gout] + hs0[32768 + b * 256 + gout];
  float h1own = hs1[b * 256 + gout] + hs1[32768 + b * 256 + gout];
  // logits weights in registers
  const int lv_ = tid >> 4, lk_ = tid & 15;
  uint4 ow0 = {0,0,0,0}, ow1 = {0,0,0,0}; float outbv = 0.f;
  if (tid < VV * 16) {
    const uint4* owp = (const uint4*)(outw + (size_t)lv_ * 256 + lk_ * 16);
    ow0 = owp[0]; ow1 = owp[1];
    outbv = outb[lv_];
  }
  if (tid < 256) {
    h0buf[0][tid] = (f16)(hs0[b * 256 + tid] + hs0[32768 + b * 256 + tid]);
    h1buf[0][tid] = (f16)(hs1[b * 256 + tid] + hs1[32768 + b * 256 + tid]);
  }
  // fill enc quarter: global rows [wq*128,+128), XOR-swizzled 16B segs
  {
    const int r = tid >> 2, q8 = tid & 3;
    const uint4* src = (const uint4*)(enc + ((size_t)b * 512 + wq * 128 + r) * 256) + q8 * 8;
    const int sw = (r & 31) << 4;
#pragma unroll
    for (int j = 0; j < 8; ++j) {
      uint4 v = src[j];
      *(uint4*)(smem + r * 512 + (((q8 * 8 + j) * 16) ^ sw)) = v;
    }
  }
  // fill encOT: transpose encO rows [wq*128,+128) cols [0,32) -> [32][128]
  {
    const int r = tid >> 2, g = tid & 3;
    if (g < 2) {
      const uint4* src = (const uint4*)(encO + ((size_t)b * 512 + wq * 128 + r) * 64 + g * 16);
#pragma unroll
      for (int u = 0; u < 2; ++u) {
        uint4 v = src[u];
        const f16* vp = (const f16*)&v;
#pragma unroll
        for (int j = 0; j < 8; ++j) encOT[(g * 16 + u * 8 + j) * 128 + r] = vp[j];
      }
    }
  }
  int tok = tseq[b * 64];
  __syncthreads();

  for (int s = 0; s < NSTEP; ++s) {
    const int cur = s & 1, nxt = cur ^ 1;
    const unsigned tag = (unsigned)(s + 1);

    // ---- P1 cell0: quarter gate rows; pub packets; own quarter -> LDS ----
    {
      float g0 = 0.f, g1 = 0.f, g2 = 0.f;
      mv3q(dwhh, gout, seg, h0buf[cur], g0, g1, g2);
      g0 += __shfl_xor(g0, 1); g0 += __shfl_xor(g0, 2); g0 += __shfl_xor(g0, 4);
      g1 += __shfl_xor(g1, 1); g1 += __shfl_xor(g1, 2); g1 += __shfl_xor(g1, 4);
      g2 += __shfl_xor(g2, 1); g2 += __shfl_xor(g2, 2); g2 += __shfl_xor(g2, 4);
      if (seg == 0) {
        const float* giP = gi0 + tok * 768;
        float r = sigm_(giP[gout] + g0 + bh00);
        float z = sigm_(giP[gout + 256] + g1 + bh01);
        float n = tanhf(giP[gout + 512] + r * (g2 + bh02));
        h0own = (1.f - z) * n + z * h0own;
      }
      float pnext = __shfl_down(h0own, 8);
      if (seg == 0) {
        h0buf[nxt][gout] = (f16)h0own;       // own quarter -> LDS directly
        if (!(o8 & 1))
          pubp(bxh0 + (gout >> 1), tag, pack2h(h0own, pnext));
      }
    }
    if (tid < 128 && (tid >> 5) != wq)       // poll partner quarters only
      ((uint32_t*)h0buf[nxt])[tid] = pollp(bxh0 + tid, tag);
    __syncthreads();             // B1: h0' gathered

    // ---- P2 cell1: quarter gate rows; pub packets; own quarter -> LDS ----
    {
      float a0 = 0.f, a1 = 0.f, a2 = 0.f;
      mv3q(dwih1, gout, seg, h0buf[nxt], a0, a1, a2);
      float c0 = 0.f, c1 = 0.f, c2 = 0.f;
      mv3q(dwhh1, gout, seg, h1buf[cur], c0, c1, c2);
      a0 += __shfl_xor(a0, 1); a0 += __shfl_xor(a0, 2); a0 += __shfl_xor(a0, 4);
      a1 += __shfl_xor(a1, 1); a1 += __shfl_xor(a1, 2); a1 += __shfl_xor(a1, 4);
      a2 += __shfl_xor(a2, 1); a2 += __shfl_xor(a2, 2); a2 += __shfl_xor(a2, 4);
      c0 += __shfl_xor(c0, 1); c0 += __shfl_xor(c0, 2); c0 += __shfl_xor(c0, 4);
      c1 += __shfl_xor(c1, 1); c1 += __shfl_xor(c1, 2); c1 += __shfl_xor(c1, 4);
      c2 += __shfl_xor(c2, 1); c2 += __shfl_xor(c2, 2); c2 += __shfl_xor(c2, 4);
      if (seg == 0) {
        float r = sigm_(a0 + bi10 + c0 + bh10);
        float z = sigm_(a1 + bi11 + c1 + bh11);
        float n = tanhf(a2 + bi12 + r * (c2 + bh12));
        h1own = (1.f - z) * n + z * h1own;
      }
      float pnext = __shfl_down(h1own, 8);
      if (seg == 0) {
        h1buf[nxt][gout] = (f16)h1own;       // own quarter -> LDS directly
        if (!(o8 & 1))
          pubp(bxh1 + (gout >> 1), tag, pack2h(h1own, pnext));
      }
    }
    if (tid < 128 && (tid >> 5) != wq)
      ((uint32_t*)h1buf[nxt])[tid] = pollp(bxh1 + tid, tag);
    __syncthreads();             // B2: h1' gathered

    // ---- P3 q: quarter rows; pub packets; own quarter -> LDS ----
    {
      float qv = mv1q(qw, gout, seg, h1buf[nxt]);
      qv += __shfl_xor(qv, 1); qv += __shfl_xor(qv, 2); qv += __shfl_xor(qv, 4);
      qv += qbv;
      float pnext = __shfl_down(qv, 8);
      if (seg == 0) {
        qsh[gout] = (f16)qv;                 // own quarter -> LDS directly
        if (!(o8 & 1))
          pubp(bxq + (gout >> 1), tag, pack2h(qv, pnext));
      }
    }
    if (tid < 128 && (tid >> 5) != wq)
      ((uint32_t*)qsh)[tid] = pollp(bxq + tid, tag);
    __syncthreads();             // B3: q gathered

    // ---- P4 scores over MY 128 LDS enc rows (local only) ----
    {
      const int r = tid >> 2, sg = tid & 3;
      const int sw = (r & 31) << 4;
      const uint4* q4 = (const uint4*)qsh;
      float s0 = 0.f, s1 = 0.f;
#pragma unroll
      for (int j = 0; j < 8; ++j) {
        int sgi = sg * 8 + j;
        uint4 ev = *(const uint4*)(smem + r * 512 + ((sgi * 16) ^ sw));
        uint4 qv = q4[sgi];
        s0 = fdot2u(ev.x, qv.x, s0); s0 = fdot2u(ev.y, qv.y, s0);
        s1 = fdot2u(ev.z, qv.z, s1); s1 = fdot2u(ev.w, qv.w, s1);
      }
      float sv = s0 + s1;
      sv += __shfl_xor(sv, 1); sv += __shfl_xor(sv, 2);
      if (sg == 0) sc[r] = sv;
    }
    __syncthreads();             // B4: sc ready

    // ---- local softmax stats ----
    float vdup = sc[tid & 127];
    float mloc = vdup;
#pragma unroll
    for (int off = 32; off; off >>= 1) mloc = fmaxf(mloc, __shfl_xor(mloc, off));
    if ((tid & 63) == 0) red[tid >> 6] = mloc;
    __syncthreads();             // B5
    float m_w = red[0];
#pragma unroll
    for (int wv = 1; wv < 8; ++wv) m_w = fmaxf(m_w, red[wv]);
    float e = 0.f;
    if (tid < 128) { e = __expf(sc[tid] - m_w); sc[tid] = e; }
    float ls = e;
#pragma unroll
    for (int off = 32; off; off >>= 1) ls += __shfl_xor(ls, off);
    if ((tid & 63) == 0) red2[tid >> 6] = ls;
    __syncthreads();             // B6: sc=exp ready + red2
    float l_w = red2[0] + red2[1] + red2[2] + red2[3]
              + red2[4] + red2[5] + red2[6] + red2[7];

    // ---- P5 weighted-encO partials (29) + (m,l); own quarter -> LDS ----
    {
      const int oo = tid >> 4, tk = tid & 15;
      if (oo < VV) {
        uint4 ev = *(const uint4*)(encOT + oo * 128 + tk * 8);
        const f16* ep = (const f16*)&ev;
        const float* wp = sc + tk * 8;
        float a = 0.f;
#pragma unroll
        for (int j = 0; j < 8; ++j) a += wp[j] * (float)ep[j];
        a += __shfl_xor(a, 1); a += __shfl_xor(a, 2);
        a += __shfl_xor(a, 4); a += __shfl_xor(a, 8);
        if (tk == 0) {
          ctxO[wq][oo] = a;                   // own quarter -> LDS directly
          pubf(bxcm + wq * 32 + oo, tag, a);
        }
      }
      if (tid == 480) { ctxO[wq][29] = m_w; pubf(bxcm + wq * 32 + 29, tag, m_w); }
      if (tid == 481) { ctxO[wq][30] = l_w; pubf(bxcm + wq * 32 + 30, tag, l_w); }
    }
    if (tid < 128 && (tid >> 5) != wq) {     // poll partner quarters only
      const int q4 = tid >> 5, ix = tid & 31;
      if (ix < 31) ctxO[q4][ix] = pollf(bxcm + q4 * 32 + ix, tag);
    }
    __syncthreads();             // B7: ctxO gathered

    // ---- P6 logits = outW@h1' + ctx-part + outb ----
    if (tid < VV * 16) {
      const uint32_t* h1u = (const uint32_t*)h1buf[nxt] + lk_ * 8;
      float acc = 0.f;
      acc = fdot2u(ow0.x, h1u[0], acc); acc = fdot2u(ow0.y, h1u[1], acc);
      acc = fdot2u(ow0.z, h1u[2], acc); acc = fdot2u(ow0.w, h1u[3], acc);
      acc = fdot2u(ow1.x, h1u[4], acc); acc = fdot2u(ow1.y, h1u[5], acc);
      acc = fdot2u(ow1.z, h1u[6], acc); acc = fdot2u(ow1.w, h1u[7], acc);
      acc += __shfl_xor(acc, 1); acc += __shfl_xor(acc, 2);
      acc += __shfl_xor(acc, 4); acc += __shfl_xor(acc, 8);
      if (lk_ == 0) {
        float m0 = ctxO[0][29], m1 = ctxO[1][29], m2 = ctxO[2][29], m3 = ctxO[3][29];
        float m = fmaxf(fmaxf(m0, m1), fmaxf(m2, m3));
        float w0 = __expf(m0 - m), w1 = __expf(m1 - m);
        float w2 = __expf(m2 - m), w3 = __expf(m3 - m);
        float l = ctxO[0][30] * w0 + ctxO[1][30] * w1
                + ctxO[2][30] * w2 + ctxO[3][30] * w3;
        float cs = ctxO[0][lv_] * w0 + ctxO[1][lv_] * w1
                 + ctxO[2][lv_] * w2 + ctxO[3][lv_] * w3;
        float lvv = acc + cs / l + outbv;
        lg[lv_] = lvv;
        if (wq == 0) out[((size_t)b * NSTEP + s) * VV + lv_] = lvv;
      }
    }
    __syncthreads();             // B8: lg ready

    // ---- argmax (identical in every WG) ----
    {
      const int lane = tid & 63;
      float val = (lane < VV) ? lg[lane] : -3.4e38f;
      int bi = lane;
#pragma unroll
      for (int off = 32; off; off >>= 1) {
        float ov = __shfl_xor(val, off);
        int oi = __shfl_xor(bi, off);
        if (ov > val || (ov == val && oi < bi)) { val = ov; bi = oi; }
      }
      tok = bi;
    }
  }

  // final hidden
  if (wq == 0 && tid < 256) {
    out[233856 + b * 256 + tid] = (float)h0buf[NSTEP & 1][tid];
    out[233856 + 32768 + b * 256 + tid] = (float)h1buf[NSTEP & 1][tid];
  }
}

extern "C" void kernel_launch(void* const* d_in, const int* in_sizes, int n_in,
                              void* d_out, int out_size, void* d_ws, size_t ws_size,
                              hipStream_t stream) {
  (void)in_sizes; (void)n_in; (void)out_size; (void)ws_size;
  const float* x     = (const float*)d_in[0];
  const int*   tseq  = (const int*)d_in[1];
  const float* eWih0 = (const float*)d_in[2];
  const float* eWhh0 = (const float*)d_in[3];
  const float* ebih0 = (const float*)d_in[4];
  const float* ebhh0 = (const float*)d_in[5];
  const float* eWih1 = (const float*)d_in[6];
  const float* eWhh1 = (const float*)d_in[7];
  const float* ebih1 = (const float*)d_in[8];
  const float* ebhh1 = (const float*)d_in[9];
  const float* e2dW  = (const float*)d_in[10];
  const float* e2db  = (const float*)d_in[11];
  const float* dWih0 = (const float*)d_in[12];
  const float* dWih1 = (const float*)d_in[13];
  const float* dWhh  = (const float*)d_in[14];
  const float* dbih  = (const float*)d_in[15];
  const float* dbhh  = (const float*)d_in[16];
  const float* qW    = (const float*)d_in[17];
  const float* qb    = (const float*)d_in[18];
  const float* outW  = (const float*)d_in[19];
  const float* outb  = (const float*)d_in[20];
  const float* emb   = (const float*)d_in[21];

  // ---- workspace ledger ----
  uint8_t* ws = (uint8_t*)d_ws;
  size_t o = 0;
  auto take = [&](size_t bytes) -> void* {
    void* p = ws + o;
    o += (bytes + 255) & ~(size_t)255;
    return p;
  };
  f16* whh0_16  = (f16*)take((size_t)2 * 768 * 256 * 2);
  f16* whh1_16  = (f16*)take((size_t)2 * 768 * 256 * 2);
  f16* wih1_16  = (f16*)take((size_t)2 * 768 * 512 * 2);
  f16* e2d_16   = (f16*)take((size_t)256 * 512 * 2);
  f16* qw_16    = (f16*)take((size_t)256 * 256 * 2);
  f16* outw_16  = (f16*)take((size_t)29 * 256 * 2);
  f16* owpad_16 = (f16*)take((size_t)64 * 256 * 2);     // outW zero-padded to 64 rows
  f16* dwih1_16 = (f16*)take((size_t)768 * 256 * 2);
  f16* dwhh_16  = (f16*)take((size_t)2 * 768 * 256 * 2);
  f16* y0   = (f16*)take((size_t)BT * 512 * 2);          // enc aliases later
  f16* y1   = (f16*)take((size_t)BT * 512 * 2);
  f16* gi   = (f16*)take((size_t)BB * CHUNK * 1536 * 2); // encO aliases later
  float* hs0 = (float*)take((size_t)2 * BB * 256 * 4);
  float* hs1 = (float*)take((size_t)2 * BB * 256 * 4);
  float* gi0 = (float*)take((size_t)VV * 768 * 4);
  u64* xh0  = (u64*)take((size_t)BB * 128 * 8);
  u64* xh1  = (u64*)take((size_t)BB * 128 * 8);
  u64* xq   = (u64*)take((size_t)BB * 128 * 8);
  u64* xcm  = (u64*)take((size_t)BB * 4 * 32 * 8);
  f16* enc  = y0;  // alias: y0 dead after last gi chunk GEMM
  f16* encO = (f16*)gi;  // alias: gi dead after last k_scan<1>

  hipMemsetAsync(hs0, 0, (size_t)2 * BB * 256 * 4, stream);
  hipMemsetAsync(hs1, 0, (size_t)2 * BB * 256 * 4, stream);
  hipMemsetAsync(xh0, 0, (size_t)BB * 128 * 8, stream);
  hipMemsetAsync(xh1, 0, (size_t)BB * 128 * 8, stream);
  hipMemsetAsync(xq,  0, (size_t)BB * 128 * 8, stream);
  hipMemsetAsync(xcm, 0, (size_t)BB * 4 * 32 * 8, stream);
  hipMemsetAsync(owpad_16, 0, (size_t)64 * 256 * 2, stream);

  auto cvt = [&](const float* s, f16* d, int n) {
    k_cvt<<<(n + 255) / 256, 256, 0, stream>>>(s, d, n);
  };
  cvt(eWhh0, whh0_16, 2 * 768 * 256);
  cvt(eWhh1, whh1_16, 2 * 768 * 256);
  cvt(eWih1, wih1_16, 2 * 768 * 512);
  cvt(e2dW,  e2d_16,  256 * 512);
  cvt(qW,    qw_16,   256 * 256);
  cvt(outW,  outw_16, 29 * 256);
  cvt(outW,  owpad_16, 29 * 256);
  cvt(dWih1, dwih1_16, 768 * 256);
  cvt(dWhh,  dwhh_16, 2 * 768 * 256);
  k_gi0<<<(VV * 768 + 255) / 256, 256, 0, stream>>>(dWih0, dbih, emb, gi0);

  // encoder layer 0
  k_scan<0><<<256, 512, 0, stream>>>(x, nullptr, (const uint32_t*)whh0_16,
                                     eWih0, ebih0, ebhh0, y0, hs0, 0, TT);

  // encoder layer 1: time-chunked gi GEMM + scan
  const long BSTR = (long)TT * 512;
  for (int c = 0; c < TT / CHUNK; ++c) {
    const int t0 = c * CHUNK;
    k_gemm<<<dim3(BB * CHUNK / 64, 12), 256, 0, stream>>>(
        y0 + (size_t)t0 * 512, wih1_16, gi, ebih1,
        512, 6, BSTR, 512, 1536, 0);
    k_gemm<<<dim3(BB * CHUNK / 64, 12), 256, 0, stream>>>(
        y0 + (size_t)(TT - 1 - t0) * 512, wih1_16 + (size_t)768 * 512, gi, ebih1 + 768,
        512, 6, BSTR, -512, 1536, 768);
    k_scan<1><<<256, 512, 0, stream>>>(nullptr, gi, (const uint32_t*)whh1_16,
                                       nullptr, nullptr, ebhh1, y1, hs1, t0, CHUNK);
  }

  // enc = y1 @ e2d^T + b   (writes into y0's region)
  k_gemm<<<dim3(BT / 64, 4), 256, 0, stream>>>(y1, e2d_16, enc, e2db,
                                               512, 30, 0, 512, 256, 0);

  // encO = enc @ outWpad^T  (BT x 64, f16)  — writes into gi's region
  k_gemm<<<dim3(BT / 64, 1), 256, 0, stream>>>(enc, owpad_16, encO, nullptr,
                                               256, 30, 0, 256, 64, 0);

  // persistent decoder: 4 WGs per batch, 512 WGs = 2 per CU
  hipFuncSetAttribute((const void*)k_decoder,
                      hipFuncAttributeMaxDynamicSharedMemorySize, SM_TOTAL);
  k_decoder<<<GQ * BB, 512, SM_TOTAL, stream>>>(dwhh_16, dwih1_16, qw_16, outw_16,
                                                enc, encO, gi0, dbih, dbhh, qb, outb,
                                                hs0, hs1, tseq,
                                                xh0, xh1, xq, xcm,
                                                (float*)d_out);
}

// Round 14
// 4362.600 us; speedup vs baseline: 1.1134x; 1.0486x over previous
//
#include <hip/hip_runtime.h>
#include <hip/hip_bf16.h>
#include <hip/hip_fp16.h>
#include <stdint.h>

// Problem dims
#define BB 128
#define TT 512
#define HH 256
#define VV 29
#define NSTEP 63
#define BT (BB*TT)
#define CHUNK 64   // layer-1 time chunk
#define GQ 4       // decoder WGs per batch

typedef _Float16 f16;
typedef _Float16 f16x2 __attribute__((ext_vector_type(2)));
typedef _Float16 f16x8 __attribute__((ext_vector_type(8)));
typedef float f32x4 __attribute__((ext_vector_type(4)));
typedef unsigned long long u64;

static __device__ __forceinline__ float fdot2u(uint32_t a, uint32_t b, float c) {
  return __builtin_amdgcn_fdot2(__builtin_bit_cast(f16x2, a),
                                __builtin_bit_cast(f16x2, b), c, false);
}
static __device__ __forceinline__ float sigm_(float x) {
  return 1.0f / (1.0f + __expf(-x));
}
// tagged exchange: (tag<<32)|payload32 in one relaxed agent-scope atomic.
// Publish via atomic exchange (coherence point); poll with s_sleep backoff.
static __device__ __forceinline__ void pubp(u64* p, unsigned tag, uint32_t pay) {
  u64 pkt = ((u64)tag << 32) | (u64)pay;
  (void)__hip_atomic_exchange(p, pkt, __ATOMIC_RELAXED, __HIP_MEMORY_SCOPE_AGENT);
}
static __device__ __forceinline__ uint32_t pollp(const u64* p, unsigned tag) {
  u64 pkt = __hip_atomic_load(p, __ATOMIC_RELAXED, __HIP_MEMORY_SCOPE_AGENT);
  while ((unsigned)(pkt >> 32) < tag) {
    __builtin_amdgcn_s_sleep(8);
    pkt = __hip_atomic_load(p, __ATOMIC_RELAXED, __HIP_MEMORY_SCOPE_AGENT);
  }
  return (uint32_t)pkt;
}
static __device__ __forceinline__ void pubf(u64* p, unsigned tag, float v) {
  pubp(p, tag, __builtin_bit_cast(uint32_t, v));
}
static __device__ __forceinline__ float pollf(const u64* p, unsigned tag) {
  return __builtin_bit_cast(float, pollp(p, tag));
}
static __device__ __forceinline__ uint32_t pack2h(float a, float b) {
  unsigned short ua = __builtin_bit_cast(unsigned short, (f16)a);
  unsigned short ub = __builtin_bit_cast(unsigned short, (f16)b);
  return (uint32_t)ua | ((uint32_t)ub << 16);
}

// ---------------- fp32 -> f16 convert ----------------
__global__ void k_cvt(const float* __restrict__ s, f16* __restrict__ d, int n) {
  int i = blockIdx.x * 256 + threadIdx.x;
  if (i < n) d[i] = (f16)s[i];
}

// ---------------- persistent GRU scan: 1 WG per (batch, dir) ----------------
// h double-buffered in LDS -> ONE barrier per step. Dual accumulators per
// gate (6 independent fdot chains) to halve dependent-chain latency.
template<int LAYER>
__global__ __launch_bounds__(512, 2)
void k_scan(const float* __restrict__ x,        // L0: (B,T,2)
            const f16* __restrict__ gi,         // L1: (B,nsteps,1536) chunk-local
            const uint32_t* __restrict__ whh,   // (2,768,128) as half2
            const float* __restrict__ wih0,     // L0: (2,768,2)
            const float* __restrict__ bih,      // L0: (2,768)
            const float* __restrict__ bhh,      // (2,768)
            f16* __restrict__ y,                // (B,T,512) [t][dir*256+p]
            float* __restrict__ hstate,         // (2,B,256) f32
            int t0, int nsteps)
{
  const int wg = blockIdx.x, b = wg >> 1, dir = wg & 1;
  const int tid = threadIdx.x, pair = tid >> 1, half = tid & 1;
  __shared__ __align__(16) uint4 hv4[2][32];   // h as f16[256], double-buffered

  uint4 w0[16], w1[16], w2[16];
  {
    const uint32_t* wp = whh + (size_t)dir * 768 * 128;
    const uint4* r0 = (const uint4*)(wp + (size_t)pair * 128 + half * 64);
    const uint4* r1 = (const uint4*)(wp + (size_t)(pair + 256) * 128 + half * 64);
    const uint4* r2 = (const uint4*)(wp + (size_t)(pair + 512) * 128 + half * 64);
#pragma unroll
    for (int i = 0; i < 16; i++) { w0[i] = r0[i]; w1[i] = r1[i]; w2[i] = r2[i]; }
  }
  const float bh0 = bhh[dir * 768 + pair];
  const float bh1 = bhh[dir * 768 + pair + 256];
  const float bh2 = bhh[dir * 768 + pair + 512];
  float bi0 = 0, bi1 = 0, bi2 = 0;
  float wi00 = 0, wi01 = 0, wi10 = 0, wi11 = 0, wi20 = 0, wi21 = 0;
  if (LAYER == 0) {
    bi0 = bih[dir * 768 + pair];
    bi1 = bih[dir * 768 + pair + 256];
    bi2 = bih[dir * 768 + pair + 512];
    wi00 = wih0[(dir * 768 + pair) * 2 + 0];
    wi01 = wih0[(dir * 768 + pair) * 2 + 1];
    wi10 = wih0[(dir * 768 + pair + 256) * 2 + 0];
    wi11 = wih0[(dir * 768 + pair + 256) * 2 + 1];
    wi20 = wih0[(dir * 768 + pair + 512) * 2 + 0];
    wi21 = wih0[(dir * 768 + pair + 512) * 2 + 1];
  }
  float* hs = hstate + ((size_t)dir * BB + b) * 256;
  float hreg = hs[pair];
  if (tid < 128) {
    f16x2 p2; p2[0] = (f16)hs[2 * tid]; p2[1] = (f16)hs[2 * tid + 1];
    ((uint32_t*)hv4[0])[tid] = __builtin_bit_cast(uint32_t, p2);
  }
  __syncthreads();

  int cb = 0;
  for (int s = 0; s < nsteps; ++s) {
    const int t = dir ? (TT - 1 - t0 - s) : (t0 + s);
    float gr, gz, gn;
    if (LAYER == 0) {
      float x0 = x[((size_t)b * TT + t) * 2 + 0];
      float x1 = x[((size_t)b * TT + t) * 2 + 1];
      gr = wi00 * x0 + wi01 * x1 + bi0;
      gz = wi10 * x0 + wi11 * x1 + bi1;
      gn = wi20 * x0 + wi21 * x1 + bi2;
    } else {
      const f16* g = gi + ((size_t)b * nsteps + s) * 1536 + dir * 768 + pair;
      gr = (float)g[0]; gz = (float)g[256]; gn = (float)g[512];
    }
    const uint4* hw = hv4[cb] + half * 16;
    float a0 = 0.f, a1 = 0.f, a2 = 0.f;
    float d0 = 0.f, d1 = 0.f, d2 = 0.f;
#pragma unroll
    for (int j = 0; j < 8; ++j) {
      uint4 hh = hw[j];
      a0 = fdot2u(w0[j].x, hh.x, a0); a0 = fdot2u(w0[j].y, hh.y, a0);
      a0 = fdot2u(w0[j].z, hh.z, a0); a0 = fdot2u(w0[j].w, hh.w, a0);
      a1 = fdot2u(w1[j].x, hh.x, a1); a1 = fdot2u(w1[j].y, hh.y, a1);
      a1 = fdot2u(w1[j].z, hh.z, a1); a1 = fdot2u(w1[j].w, hh.w, a1);
      a2 = fdot2u(w2[j].x, hh.x, a2); a2 = fdot2u(w2[j].y, hh.y, a2);
      a2 = fdot2u(w2[j].z, hh.z, a2); a2 = fdot2u(w2[j].w, hh.w, a2);
    }
#pragma unroll
    for (int j = 8; j < 16; ++j) {
      uint4 hh = hw[j];
      d0 = fdot2u(w0[j].x, hh.x, d0); d0 = fdot2u(w0[j].y, hh.y, d0);
      d0 = fdot2u(w0[j].z, hh.z, d0); d0 = fdot2u(w0[j].w, hh.w, d0);
      d1 = fdot2u(w1[j].x, hh.x, d1); d1 = fdot2u(w1[j].y, hh.y, d1);
      d1 = fdot2u(w1[j].z, hh.z, d1); d1 = fdot2u(w1[j].w, hh.w, d1);
      d2 = fdot2u(w2[j].x, hh.x, d2); d2 = fdot2u(w2[j].y, hh.y, d2);
      d2 = fdot2u(w2[j].z, hh.z, d2); d2 = fdot2u(w2[j].w, hh.w, d2);
    }
    a0 += d0; a1 += d1; a2 += d2;
    a0 += __shfl_xor(a0, 1);
    a1 += __shfl_xor(a1, 1);
    a2 += __shfl_xor(a2, 1);

    float r = sigm_(gr + a0 + bh0);
    float z = sigm_(gz + a1 + bh1);
    float n = tanhf(gn + r * (a2 + bh2));
    float hn = (1.0f - z) * n + z * hreg;
    hreg = hn;
    if (half == 0) {
      y[((size_t)b * TT + t) * 512 + dir * 256 + pair] = (f16)hn;
      ((f16*)hv4[cb ^ 1])[pair] = (f16)hn;   // write OTHER buffer
    }
    __syncthreads();  // nxt buffer complete; cur reads all done (pre-barrier)
    cb ^= 1;
  }
  if (half == 0) hs[pair] = hreg;
}

// ---------------- f16 MFMA GEMM: C = Arows @ Bt^T + bias ---------------------
__global__ __launch_bounds__(256)
void k_gemm(const f16* __restrict__ A, const f16* __restrict__ Bt,
            f16* __restrict__ C, const float* __restrict__ bias,
            int K, int shift, long bstride, int inner, int ldc, int coloff)
{
  const int m0 = blockIdx.x * 64, n0 = blockIdx.y * 64;
  const int tid = threadIdx.x, lane = tid & 63, wv = tid >> 6;
  __shared__ __align__(16) f16 As[64 * 40];
  __shared__ __align__(16) f16 Bs[64 * 40];
  f32x4 acc[4] = {{0,0,0,0},{0,0,0,0},{0,0,0,0},{0,0,0,0}};
  const int lrow = tid >> 2, lseg = tid & 3;
  const int ml = lane & 15, quad = lane >> 4;
  const int r = m0 + lrow;
  const f16* arow = A + (long)(r >> shift) * bstride
                      + (long)(r & ((1 << shift) - 1)) * inner;
  const f16* brow = Bt + (size_t)(n0 + lrow) * K;
  for (int k0 = 0; k0 < K; k0 += 32) {
    uint4 av = *(const uint4*)(arow + k0 + lseg * 8);
    uint4 bv = *(const uint4*)(brow + k0 + lseg * 8);
    __syncthreads();
    *(uint4*)(As + lrow * 40 + lseg * 8) = av;
    *(uint4*)(Bs + lrow * 40 + lseg * 8) = bv;
    __syncthreads();
    f16x8 af = *(const f16x8*)(As + (wv * 16 + ml) * 40 + quad * 8);
#pragma unroll
    for (int ns = 0; ns < 4; ++ns) {
      f16x8 bf = *(const f16x8*)(Bs + (ns * 16 + ml) * 40 + quad * 8);
      acc[ns] = __builtin_amdgcn_mfma_f32_16x16x32_f16(af, bf, acc[ns], 0, 0, 0);
    }
  }
#pragma unroll
  for (int ns = 0; ns < 4; ++ns) {
#pragma unroll
    for (int rr = 0; rr < 4; ++rr) {
      int row = m0 + wv * 16 + quad * 4 + rr;
      int col = n0 + ns * 16 + ml;
      float v = acc[ns][rr];
      if (bias) v += bias[col];
      C[(size_t)row * ldc + coloff + col] = (f16)v;
    }
  }
}

// ---------------- gi0[v][row] = dWih0 @ emb[v] + dbih  (29 x 768, f32) -------
__global__ void k_gi0(const float* __restrict__ dWih0, const float* __restrict__ dbih,
                      const float* __restrict__ emb, float* __restrict__ gi0) {
  int i = blockIdx.x * 256 + threadIdx.x;
  if (i >= VV * 768) return;
  int v = i / 768, row = i - v * 768;
  float a = dbih[row];
#pragma unroll
  for (int e = 0; e < 8; ++e) a += dWih0[row * 8 + e] * emb[v * 8 + e];
  gi0[i] = a;
}

// ---- quarter matvec: 3 rows (row0,+256,+512), k-slice seg*32..+32, batched --
static __device__ __forceinline__ void mv3q(const f16* __restrict__ W, int row0, int seg,
                                            const f16* __restrict__ hsh,
                                            float& g0, float& g1, float& g2) {
  const uint4* w0 = (const uint4*)(W + (size_t)row0 * 256 + seg * 32);
  const uint4* w1 = (const uint4*)(W + ((size_t)row0 + 256) * 256 + seg * 32);
  const uint4* w2 = (const uint4*)(W + ((size_t)row0 + 512) * 256 + seg * 32);
  const uint4* hv = (const uint4*)(hsh + seg * 32);
  uint4 aq[4], bq[4], cq[4], hq[4];
#pragma unroll
  for (int j = 0; j < 4; ++j) {
    aq[j] = w0[j]; bq[j] = w1[j]; cq[j] = w2[j]; hq[j] = hv[j];
  }
#pragma unroll
  for (int j = 0; j < 4; ++j) {
    g0 = fdot2u(aq[j].x, hq[j].x, g0); g0 = fdot2u(aq[j].y, hq[j].y, g0);
    g0 = fdot2u(aq[j].z, hq[j].z, g0); g0 = fdot2u(aq[j].w, hq[j].w, g0);
    g1 = fdot2u(bq[j].x, hq[j].x, g1); g1 = fdot2u(bq[j].y, hq[j].y, g1);
    g1 = fdot2u(bq[j].z, hq[j].z, g1); g1 = fdot2u(bq[j].w, hq[j].w, g1);
    g2 = fdot2u(cq[j].x, hq[j].x, g2); g2 = fdot2u(cq[j].y, hq[j].y, g2);
    g2 = fdot2u(cq[j].z, hq[j].z, g2); g2 = fdot2u(cq[j].w, hq[j].w, g2);
  }
}
// single row, k-slice seg*32..+32
static __device__ __forceinline__ float mv1q(const f16* __restrict__ W, int row, int seg,
                                             const f16* __restrict__ hsh) {
  const uint4* w = (const uint4*)(W + (size_t)row * 256 + seg * 32);
  const uint4* hv = (const uint4*)(hsh + seg * 32);
  uint4 aq[4], hq[4];
#pragma unroll
  for (int j = 0; j < 4; ++j) { aq[j] = w[j]; hq[j] = hv[j]; }
  float g = 0.f;
#pragma unroll
  for (int j = 0; j < 4; ++j) {
    g = fdot2u(aq[j].x, hq[j].x, g); g = fdot2u(aq[j].y, hq[j].y, g);
    g = fdot2u(aq[j].z, hq[j].z, g); g = fdot2u(aq[j].w, hq[j].w, g);
  }
  return g;
}

// ---------------- decoder LDS layout (dynamic, ~76 KB -> 2 WG/CU) ------------
#define SM_ENC    0        // 128 rows x 512 B (XOR-swizzled)
#define SM_ENCO   65536    // encOT: [32][128] f16 (rows 0..28 = outW@enc)
#define SM_SC     73728    // 128 f32 local scores / exp weights
#define SM_H0     74240    // f16[2][256]
#define SM_H1     75264    // f16[2][256]
#define SM_Q      76288    // f16[256]
#define SM_RED    76800    // f32[8]
#define SM_RED2   76832    // f32[8]
#define SM_CTXO   76864    // f32[4][32] gathered encO partials + (m,l)
#define SM_LG     77376    // f32[32]
#define SM_TOTAL  77568

// ------ persistent decoder: 4 WGs per batch (quarter-split), 2 WG/CU ---------
// R11 protocol exactly; ONLY change: XCD-grouped (wq,b) relabeling so each
// XCD hosts a single weight quarter (per-XCD weight set 1.33MB -> 326KB).
// blk%8 -> XCD (round-robin dispatch assumption): wq=(blk&7)>>1, b=(blk>>3)*2+(blk&1).
__global__ __launch_bounds__(512, 4)
void k_decoder(const f16* __restrict__ dwhh,   // (2,768,256)
               const f16* __restrict__ dwih1,  // (768,256)
               const f16* __restrict__ qw,     // (256,256)
               const f16* __restrict__ outw,   // (29,256)
               const f16* __restrict__ enc,    // (B,512,256)
               const f16* __restrict__ encO,   // (B,512,64): outWpad @ enc
               const float* __restrict__ gi0,  // (29,768)
               const float* __restrict__ dbih, // (2,768)
               const float* __restrict__ dbhh, // (2,768)
               const float* __restrict__ qb, const float* __restrict__ outb,
               const float* __restrict__ hs0, const float* __restrict__ hs1,
               const int* __restrict__ tseq,
               u64* __restrict__ xh0,          // (B,128) f16-pair packets
               u64* __restrict__ xh1,          // (B,128)
               u64* __restrict__ xq,           // (B,128)
               u64* __restrict__ xcm,          // (B,4,32): 0..28 partials, 29=m, 30=l
               float* __restrict__ out)
{
  extern __shared__ __align__(16) char smem[];
  f16* encOT = (f16*)(smem + SM_ENCO);               // [32][128]
  float* sc   = (float*)(smem + SM_SC);
  f16 (*h0buf)[256] = (f16(*)[256])(smem + SM_H0);
  f16 (*h1buf)[256] = (f16(*)[256])(smem + SM_H1);
  f16* qsh  = (f16*)(smem + SM_Q);
  float* red  = (float*)(smem + SM_RED);
  float* red2 = (float*)(smem + SM_RED2);
  float (*ctxO)[32] = (float(*)[32])(smem + SM_CTXO);
  float* lg  = (float*)(smem + SM_LG);

  const int tid = threadIdx.x;
  const int blk = blockIdx.x;
  const int wq = (blk & 7) >> 1;                    // XCD-grouped quarter
  const int b  = ((blk >> 3) << 1) | (blk & 1);     // bijective batch relabel
  const int o8 = tid >> 3, seg = tid & 7, gout = wq * 64 + o8;
  const f16* dwhh1 = dwhh + (size_t)768 * 256;

  u64* bxh0 = xh0 + (size_t)b * 128;
  u64* bxh1 = xh1 + (size_t)b * 128;
  u64* bxq  = xq  + (size_t)b * 128;
  u64* bxcm = xcm + (size_t)b * 4 * 32;

  // hoisted constants (per owner row gout)
  const float bh00 = dbhh[gout], bh01 = dbhh[gout + 256], bh02 = dbhh[gout + 512];
  const float bi10 = dbih[768 + gout], bi11 = dbih[768 + gout + 256], bi12 = dbih[768 + gout + 512];
  const float bh10 = dbhh[768 + gout], bh11 = dbhh[768 + gout + 256], bh12 = dbhh[768 + gout + 512];
  const float qbv = qb[gout];
  float h0own = hs0[b * 256 + gout] + hs0[32768 + b * 256 + gout];
  float h1own = hs1[b * 256 + gout] + hs1[32768 + b * 256 + gout];
  // logits weights in registers
  const int lv_ = tid >> 4, lk_ = tid & 15;
  uint4 ow0 = {0,0,0,0}, ow1 = {0,0,0,0}; float outbv = 0.f;
  if (tid < VV * 16) {
    const uint4* owp = (const uint4*)(outw + (size_t)lv_ * 256 + lk_ * 16);
    ow0 = owp[0]; ow1 = owp[1];
    outbv = outb[lv_];
  }
  if (tid < 256) {
    h0buf[0][tid] = (f16)(hs0[b * 256 + tid] + hs0[32768 + b * 256 + tid]);
    h1buf[0][tid] = (f16)(hs1[b * 256 + tid] + hs1[32768 + b * 256 + tid]);
  }
  // fill enc quarter: global rows [wq*128,+128), XOR-swizzled 16B segs
  {
    const int r = tid >> 2, q8 = tid & 3;
    const uint4* src = (const uint4*)(enc + ((size_t)b * 512 + wq * 128 + r) * 256) + q8 * 8;
    const int sw = (r & 31) << 4;
#pragma unroll
    for (int j = 0; j < 8; ++j) {
      uint4 v = src[j];
      *(uint4*)(smem + r * 512 + (((q8 * 8 + j) * 16) ^ sw)) = v;
    }
  }
  // fill encOT: transpose encO rows [wq*128,+128) cols [0,32) -> [32][128]
  {
    const int r = tid >> 2, g = tid & 3;
    if (g < 2) {
      const uint4* src = (const uint4*)(encO + ((size_t)b * 512 + wq * 128 + r) * 64 + g * 16);
#pragma unroll
      for (int u = 0; u < 2; ++u) {
        uint4 v = src[u];
        const f16* vp = (const f16*)&v;
#pragma unroll
        for (int j = 0; j < 8; ++j) encOT[(g * 16 + u * 8 + j) * 128 + r] = vp[j];
      }
    }
  }
  int tok = tseq[b * 64];
  __syncthreads();

  for (int s = 0; s < NSTEP; ++s) {
    const int cur = s & 1, nxt = cur ^ 1;
    const unsigned tag = (unsigned)(s + 1);

    // ---- P1 cell0: quarter gate rows; publish f16-pair packets ----
    {
      float g0 = 0.f, g1 = 0.f, g2 = 0.f;
      mv3q(dwhh, gout, seg, h0buf[cur], g0, g1, g2);
      g0 += __shfl_xor(g0, 1); g0 += __shfl_xor(g0, 2); g0 += __shfl_xor(g0, 4);
      g1 += __shfl_xor(g1, 1); g1 += __shfl_xor(g1, 2); g1 += __shfl_xor(g1, 4);
      g2 += __shfl_xor(g2, 1); g2 += __shfl_xor(g2, 2); g2 += __shfl_xor(g2, 4);
      if (seg == 0) {
        const float* giP = gi0 + tok * 768;
        float r = sigm_(giP[gout] + g0 + bh00);
        float z = sigm_(giP[gout + 256] + g1 + bh01);
        float n = tanhf(giP[gout + 512] + r * (g2 + bh02));
        h0own = (1.f - z) * n + z * h0own;
      }
      float pnext = __shfl_down(h0own, 8);
      if (seg == 0 && !(o8 & 1))
        pubp(bxh0 + (gout >> 1), tag, pack2h(h0own, pnext));
    }
    if (tid < 128) ((uint32_t*)h0buf[nxt])[tid] = pollp(bxh0 + tid, tag);
    __syncthreads();             // B1: h0' gathered

    // ---- P2 cell1: quarter gate rows ----
    {
      float a0 = 0.f, a1 = 0.f, a2 = 0.f;
      mv3q(dwih1, gout, seg, h0buf[nxt], a0, a1, a2);
      float c0 = 0.f, c1 = 0.f, c2 = 0.f;
      mv3q(dwhh1, gout, seg, h1buf[cur], c0, c1, c2);
      a0 += __shfl_xor(a0, 1); a0 += __shfl_xor(a0, 2); a0 += __shfl_xor(a0, 4);
      a1 += __shfl_xor(a1, 1); a1 += __shfl_xor(a1, 2); a1 += __shfl_xor(a1, 4);
      a2 += __shfl_xor(a2, 1); a2 += __shfl_xor(a2, 2); a2 += __shfl_xor(a2, 4);
      c0 += __shfl_xor(c0, 1); c0 += __shfl_xor(c0, 2); c0 += __shfl_xor(c0, 4);
      c1 += __shfl_xor(c1, 1); c1 += __shfl_xor(c1, 2); c1 += __shfl_xor(c1, 4);
      c2 += __shfl_xor(c2, 1); c2 += __shfl_xor(c2, 2); c2 += __shfl_xor(c2, 4);
      if (seg == 0) {
        float r = sigm_(a0 + bi10 + c0 + bh10);
        float z = sigm_(a1 + bi11 + c1 + bh11);
        float n = tanhf(a2 + bi12 + r * (c2 + bh12));
        h1own = (1.f - z) * n + z * h1own;
      }
      float pnext = __shfl_down(h1own, 8);
      if (seg == 0 && !(o8 & 1))
        pubp(bxh1 + (gout >> 1), tag, pack2h(h1own, pnext));
    }
    if (tid < 128) ((uint32_t*)h1buf[nxt])[tid] = pollp(bxh1 + tid, tag);
    __syncthreads();             // B2: h1' gathered

    // ---- P3 q: quarter rows ----
    {
      float qv = mv1q(qw, gout, seg, h1buf[nxt]);
      qv += __shfl_xor(qv, 1); qv += __shfl_xor(qv, 2); qv += __shfl_xor(qv, 4);
      qv += qbv;
      float pnext = __shfl_down(qv, 8);
      if (seg == 0 && !(o8 & 1))
        pubp(bxq + (gout >> 1), tag, pack2h(qv, pnext));
    }
    if (tid < 128) ((uint32_t*)qsh)[tid] = pollp(bxq + tid, tag);
    __syncthreads();             // B3: q gathered

    // ---- P4 scores over MY 128 LDS enc rows (local only) ----
    {
      const int r = tid >> 2, sg = tid & 3;
      const int sw = (r & 31) << 4;
      const uint4* q4 = (const uint4*)qsh;
      float s0 = 0.f, s1 = 0.f;
#pragma unroll
      for (int j = 0; j < 8; ++j) {
        int sgi = sg * 8 + j;
        uint4 ev = *(const uint4*)(smem + r * 512 + ((sgi * 16) ^ sw));
        uint4 qv = q4[sgi];
        s0 = fdot2u(ev.x, qv.x, s0); s0 = fdot2u(ev.y, qv.y, s0);
        s1 = fdot2u(ev.z, qv.z, s1); s1 = fdot2u(ev.w, qv.w, s1);
      }
      float sv = s0 + s1;
      sv += __shfl_xor(sv, 1); sv += __shfl_xor(sv, 2);
      if (sg == 0) sc[r] = sv;
    }
    __syncthreads();             // B4: sc ready

    // ---- local softmax stats ----
    float vdup = sc[tid & 127];
    float mloc = vdup;
#pragma unroll
    for (int off = 32; off; off >>= 1) mloc = fmaxf(mloc, __shfl_xor(mloc, off));
    if ((tid & 63) == 0) red[tid >> 6] = mloc;
    __syncthreads();             // B5
    float m_w = red[0];
#pragma unroll
    for (int wv = 1; wv < 8; ++wv) m_w = fmaxf(m_w, red[wv]);
    float e = 0.f;
    if (tid < 128) { e = __expf(sc[tid] - m_w); sc[tid] = e; }
    float ls = e;
#pragma unroll
    for (int off = 32; off; off >>= 1) ls += __shfl_xor(ls, off);
    if ((tid & 63) == 0) red2[tid >> 6] = ls;
    __syncthreads();             // B6: sc=exp ready + red2
    float l_w = red2[0] + red2[1] + red2[2] + red2[3]
              + red2[4] + red2[5] + red2[6] + red2[7];

    // ---- P5 weighted-encO partials (29 outputs) + publish (m,l) ----
    {
      const int oo = tid >> 4, tk = tid & 15;
      if (oo < VV) {
        uint4 ev = *(const uint4*)(encOT + oo * 128 + tk * 8);
        const f16* ep = (const f16*)&ev;
        const float* wp = sc + tk * 8;
        float a = 0.f;
#pragma unroll
        for (int j = 0; j < 8; ++j) a += wp[j] * (float)ep[j];
        a += __shfl_xor(a, 1); a += __shfl_xor(a, 2);
        a += __shfl_xor(a, 4); a += __shfl_xor(a, 8);
        if (tk == 0) pubf(bxcm + wq * 32 + oo, tag, a);
      }
      if (tid == 480) pubf(bxcm + wq * 32 + 29, tag, m_w);
      if (tid == 481) pubf(bxcm + wq * 32 + 30, tag, l_w);
    }
    if (tid < 128) {
      const int q4 = tid >> 5, ix = tid & 31;
      if (ix < 31) ctxO[q4][ix] = pollf(bxcm + q4 * 32 + ix, tag);
    }
    __syncthreads();             // B7: ctxO gathered

    // ---- P6 logits = outW@h1' + ctx-part + outb ----
    if (tid < VV * 16) {
      const uint32_t* h1u = (const uint32_t*)h1buf[nxt] + lk_ * 8;
      float acc = 0.f;
      acc = fdot2u(ow0.x, h1u[0], acc); acc = fdot2u(ow0.y, h1u[1], acc);
      acc = fdot2u(ow0.z, h1u[2], acc); acc = fdot2u(ow0.w, h1u[3], acc);
      acc = fdot2u(ow1.x, h1u[4], acc); acc = fdot2u(ow1.y, h1u[5], acc);
      acc = fdot2u(ow1.z, h1u[6], acc); acc = fdot2u(ow1.w, h1u[7], acc);
      acc += __shfl_xor(acc, 1); acc += __shfl_xor(acc, 2);
      acc += __shfl_xor(acc, 4); acc += __shfl_xor(acc, 8);
      if (lk_ == 0) {
        float m0 = ctxO[0][29], m1 = ctxO[1][29], m2 = ctxO[2][29], m3 = ctxO[3][29];
        float m = fmaxf(fmaxf(m0, m1), fmaxf(m2, m3));
        float w0 = __expf(m0 - m), w1 = __expf(m1 - m);
        float w2 = __expf(m2 - m), w3 = __expf(m3 - m);
        float l = ctxO[0][30] * w0 + ctxO[1][30] * w1
                + ctxO[2][30] * w2 + ctxO[3][30] * w3;
        float cs = ctxO[0][lv_] * w0 + ctxO[1][lv_] * w1
                 + ctxO[2][lv_] * w2 + ctxO[3][lv_] * w3;
        float lvv = acc + cs / l + outbv;
        lg[lv_] = lvv;
        if (wq == 0) out[((size_t)b * NSTEP + s) * VV + lv_] = lvv;
      }
    }
    __syncthreads();             // B8: lg ready

    // ---- argmax (identical in every WG) ----
    {
      const int lane = tid & 63;
      float val = (lane < VV) ? lg[lane] : -3.4e38f;
      int bi = lane;
#pragma unroll
      for (int off = 32; off; off >>= 1) {
        float ov = __shfl_xor(val, off);
        int oi = __shfl_xor(bi, off);
        if (ov > val || (ov == val && oi < bi)) { val = ov; bi = oi; }
      }
      tok = bi;
    }
  }

  // final hidden
  if (wq == 0 && tid < 256) {
    out[233856 + b * 256 + tid] = (float)h0buf[NSTEP & 1][tid];
    out[233856 + 32768 + b * 256 + tid] = (float)h1buf[NSTEP & 1][tid];
  }
}

extern "C" void kernel_launch(void* const* d_in, const int* in_sizes, int n_in,
                              void* d_out, int out_size, void* d_ws, size_t ws_size,
                              hipStream_t stream) {
  (void)in_sizes; (void)n_in; (void)out_size; (void)ws_size;
  const float* x     = (const float*)d_in[0];
  const int*   tseq  = (const int*)d_in[1];
  const float* eWih0 = (const float*)d_in[2];
  const float* eWhh0 = (const float*)d_in[3];
  const float* ebih0 = (const float*)d_in[4];
  const float* ebhh0 = (const float*)d_in[5];
  const float* eWih1 = (const float*)d_in[6];
  const float* eWhh1 = (const float*)d_in[7];
  const float* ebih1 = (const float*)d_in[8];
  const float* ebhh1 = (const float*)d_in[9];
  const float* e2dW  = (const float*)d_in[10];
  const float* e2db  = (const float*)d_in[11];
  const float* dWih0 = (const float*)d_in[12];
  const float* dWih1 = (const float*)d_in[13];
  const float* dWhh  = (const float*)d_in[14];
  const float* dbih  = (const float*)d_in[15];
  const float* dbhh  = (const float*)d_in[16];
  const float* qW    = (const float*)d_in[17];
  const float* qb    = (const float*)d_in[18];
  const float* outW  = (const float*)d_in[19];
  const float* outb  = (const float*)d_in[20];
  const float* emb   = (const float*)d_in[21];

  // ---- workspace ledger ----
  uint8_t* ws = (uint8_t*)d_ws;
  size_t o = 0;
  auto take = [&](size_t bytes) -> void* {
    void* p = ws + o;
    o += (bytes + 255) & ~(size_t)255;
    return p;
  };
  f16* whh0_16  = (f16*)take((size_t)2 * 768 * 256 * 2);
  f16* whh1_16  = (f16*)take((size_t)2 * 768 * 256 * 2);
  f16* wih1_16  = (f16*)take((size_t)2 * 768 * 512 * 2);
  f16* e2d_16   = (f16*)take((size_t)256 * 512 * 2);
  f16* qw_16    = (f16*)take((size_t)256 * 256 * 2);
  f16* outw_16  = (f16*)take((size_t)29 * 256 * 2);
  f16* owpad_16 = (f16*)take((size_t)64 * 256 * 2);     // outW zero-padded to 64 rows
  f16* dwih1_16 = (f16*)take((size_t)768 * 256 * 2);
  f16* dwhh_16  = (f16*)take((size_t)2 * 768 * 256 * 2);
  f16* y0   = (f16*)take((size_t)BT * 512 * 2);          // enc aliases later
  f16* y1   = (f16*)take((size_t)BT * 512 * 2);
  f16* gi   = (f16*)take((size_t)BB * CHUNK * 1536 * 2); // encO aliases later
  float* hs0 = (float*)take((size_t)2 * BB * 256 * 4);
  float* hs1 = (float*)take((size_t)2 * BB * 256 * 4);
  float* gi0 = (float*)take((size_t)VV * 768 * 4);
  u64* xh0  = (u64*)take((size_t)BB * 128 * 8);
  u64* xh1  = (u64*)take((size_t)BB * 128 * 8);
  u64* xq   = (u64*)take((size_t)BB * 128 * 8);
  u64* xcm  = (u64*)take((size_t)BB * 4 * 32 * 8);
  f16* enc  = y0;  // alias: y0 dead after last gi chunk GEMM
  f16* encO = (f16*)gi;  // alias: gi dead after last k_scan<1>

  hipMemsetAsync(hs0, 0, (size_t)2 * BB * 256 * 4, stream);
  hipMemsetAsync(hs1, 0, (size_t)2 * BB * 256 * 4, stream);
  hipMemsetAsync(xh0, 0, (size_t)BB * 128 * 8, stream);
  hipMemsetAsync(xh1, 0, (size_t)BB * 128 * 8, stream);
  hipMemsetAsync(xq,  0, (size_t)BB * 128 * 8, stream);
  hipMemsetAsync(xcm, 0, (size_t)BB * 4 * 32 * 8, stream);
  hipMemsetAsync(owpad_16, 0, (size_t)64 * 256 * 2, stream);

  auto cvt = [&](const float* s, f16* d, int n) {
    k_cvt<<<(n + 255) / 256, 256, 0, stream>>>(s, d, n);
  };
  cvt(eWhh0, whh0_16, 2 * 768 * 256);
  cvt(eWhh1, whh1_16, 2 * 768 * 256);
  cvt(eWih1, wih1_16, 2 * 768 * 512);
  cvt(e2dW,  e2d_16,  256 * 512);
  cvt(qW,    qw_16,   256 * 256);
  cvt(outW,  outw_16, 29 * 256);
  cvt(outW,  owpad_16, 29 * 256);
  cvt(dWih1, dwih1_16, 768 * 256);
  cvt(dWhh,  dwhh_16, 2 * 768 * 256);
  k_gi0<<<(VV * 768 + 255) / 256, 256, 0, stream>>>(dWih0, dbih, emb, gi0);

  // encoder layer 0
  k_scan<0><<<256, 512, 0, stream>>>(x, nullptr, (const uint32_t*)whh0_16,
                                     eWih0, ebih0, ebhh0, y0, hs0, 0, TT);

  // encoder layer 1: time-chunked gi GEMM + scan
  const long BSTR = (long)TT * 512;
  for (int c = 0; c < TT / CHUNK; ++c) {
    const int t0 = c * CHUNK;
    k_gemm<<<dim3(BB * CHUNK / 64, 12), 256, 0, stream>>>(
        y0 + (size_t)t0 * 512, wih1_16, gi, ebih1,
        512, 6, BSTR, 512, 1536, 0);
    k_gemm<<<dim3(BB * CHUNK / 64, 12), 256, 0, stream>>>(
        y0 + (size_t)(TT - 1 - t0) * 512, wih1_16 + (size_t)768 * 512, gi, ebih1 + 768,
        512, 6, BSTR, -512, 1536, 768);
    k_scan<1><<<256, 512, 0, stream>>>(nullptr, gi, (const uint32_t*)whh1_16,
                                       nullptr, nullptr, ebhh1, y1, hs1, t0, CHUNK);
  }

  // enc = y1 @ e2d^T + b   (writes into y0's region)
  k_gemm<<<dim3(BT / 64, 4), 256, 0, stream>>>(y1, e2d_16, enc, e2db,
                                               512, 30, 0, 512, 256, 0);

  // encO = enc @ outWpad^T  (BT x 64, f16)  — writes into gi's region
  k_gemm<<<dim3(BT / 64, 1), 256, 0, stream>>>(enc, owpad_16, encO, nullptr,
                                               256, 30, 0, 256, 64, 0);

  // persistent decoder: 4 WGs per batch, 512 WGs = 2 per CU
  hipFuncSetAttribute((const void*)k_decoder,
                      hipFuncAttributeMaxDynamicSharedMemorySize, SM_TOTAL);
  k_decoder<<<GQ * BB, 512, SM_TOTAL, stream>>>(dwhh_16, dwih1_16, qw_16, outw_16,
                                                enc, encO, gi0, dbih, dbhh, qb, outb,
                                                hs0, hs1, tseq,
                                                xh0, xh1, xq, xcm,
                                                (float*)d_out);
}

// Round 16
// 3250.404 us; speedup vs baseline: 1.4943x; 1.3422x over previous
//
#include <hip/hip_runtime.h>
#include <hip/hip_bf16.h>
#include <hip/hip_fp16.h>
#include <stdint.h>

// Problem dims
#define BB 128
#define TT 512
#define HH 256
#define VV 29
#define NSTEP 63
#define BT (BB*TT)
#define CHUNK 64   // layer-1 time chunk
#define GQ 4       // decoder quarters per batch

typedef _Float16 f16;
typedef _Float16 f16x2 __attribute__((ext_vector_type(2)));
typedef _Float16 f16x8 __attribute__((ext_vector_type(8)));
typedef float f32x4 __attribute__((ext_vector_type(4)));
typedef unsigned long long u64;

static __device__ __forceinline__ float fdot2u(uint32_t a, uint32_t b, float c) {
  return __builtin_amdgcn_fdot2(__builtin_bit_cast(f16x2, a),
                                __builtin_bit_cast(f16x2, b), c, false);
}
static __device__ __forceinline__ float sigm_(float x) {
  return 1.0f / (1.0f + __expf(-x));
}
// tagged exchange: (tag<<32)|payload32 in one relaxed agent-scope atomic.
static __device__ __forceinline__ void pubp(u64* p, unsigned tag, uint32_t pay) {
  u64 pkt = ((u64)tag << 32) | (u64)pay;
  (void)__hip_atomic_exchange(p, pkt, __ATOMIC_RELAXED, __HIP_MEMORY_SCOPE_AGENT);
}
static __device__ __forceinline__ uint32_t pollp(const u64* p, unsigned tag) {
  u64 pkt = __hip_atomic_load(p, __ATOMIC_RELAXED, __HIP_MEMORY_SCOPE_AGENT);
  while ((unsigned)(pkt >> 32) < tag) {
    __builtin_amdgcn_s_sleep(8);
    pkt = __hip_atomic_load(p, __ATOMIC_RELAXED, __HIP_MEMORY_SCOPE_AGENT);
  }
  return (uint32_t)pkt;
}
static __device__ __forceinline__ void pubf(u64* p, unsigned tag, float v) {
  pubp(p, tag, __builtin_bit_cast(uint32_t, v));
}
static __device__ __forceinline__ float pollf(const u64* p, unsigned tag) {
  return __builtin_bit_cast(float, pollp(p, tag));
}
static __device__ __forceinline__ uint32_t pack2h(float a, float b) {
  unsigned short ua = __builtin_bit_cast(unsigned short, (f16)a);
  unsigned short ub = __builtin_bit_cast(unsigned short, (f16)b);
  return (uint32_t)ua | ((uint32_t)ub << 16);
}

// ---------------- fp32 -> f16 convert ----------------
__global__ void k_cvt(const float* __restrict__ s, f16* __restrict__ d, int n) {
  int i = blockIdx.x * 256 + threadIdx.x;
  if (i < n) d[i] = (f16)s[i];
}

// ---------------- persistent GRU scan: 1 WG per (batch, dir) ----------------
template<int LAYER>
__global__ __launch_bounds__(512, 2)
void k_scan(const float* __restrict__ x,        // L0: (B,T,2)
            const f16* __restrict__ gi,         // L1: (B,nsteps,1536) chunk-local
            const uint32_t* __restrict__ whh,   // (2,768,128) as half2
            const float* __restrict__ wih0,     // L0: (2,768,2)
            const float* __restrict__ bih,      // L0: (2,768)
            const float* __restrict__ bhh,      // (2,768)
            f16* __restrict__ y,                // (B,T,512) [t][dir*256+p]
            float* __restrict__ hstate,         // (2,B,256) f32
            int t0, int nsteps)
{
  const int wg = blockIdx.x, b = wg >> 1, dir = wg & 1;
  const int tid = threadIdx.x, pair = tid >> 1, half = tid & 1;
  __shared__ __align__(16) uint4 hv4[2][32];   // h as f16[256], double-buffered

  uint4 w0[16], w1[16], w2[16];
  {
    const uint32_t* wp = whh + (size_t)dir * 768 * 128;
    const uint4* r0 = (const uint4*)(wp + (size_t)pair * 128 + half * 64);
    const uint4* r1 = (const uint4*)(wp + (size_t)(pair + 256) * 128 + half * 64);
    const uint4* r2 = (const uint4*)(wp + (size_t)(pair + 512) * 128 + half * 64);
#pragma unroll
    for (int i = 0; i < 16; i++) { w0[i] = r0[i]; w1[i] = r1[i]; w2[i] = r2[i]; }
  }
  const float bh0 = bhh[dir * 768 + pair];
  const float bh1 = bhh[dir * 768 + pair + 256];
  const float bh2 = bhh[dir * 768 + pair + 512];
  float bi0 = 0, bi1 = 0, bi2 = 0;
  float wi00 = 0, wi01 = 0, wi10 = 0, wi11 = 0, wi20 = 0, wi21 = 0;
  if (LAYER == 0) {
    bi0 = bih[dir * 768 + pair];
    bi1 = bih[dir * 768 + pair + 256];
    bi2 = bih[dir * 768 + pair + 512];
    wi00 = wih0[(dir * 768 + pair) * 2 + 0];
    wi01 = wih0[(dir * 768 + pair) * 2 + 1];
    wi10 = wih0[(dir * 768 + pair + 256) * 2 + 0];
    wi11 = wih0[(dir * 768 + pair + 256) * 2 + 1];
    wi20 = wih0[(dir * 768 + pair + 512) * 2 + 0];
    wi21 = wih0[(dir * 768 + pair + 512) * 2 + 1];
  }
  float* hs = hstate + ((size_t)dir * BB + b) * 256;
  float hreg = hs[pair];
  if (tid < 128) {
    f16x2 p2; p2[0] = (f16)hs[2 * tid]; p2[1] = (f16)hs[2 * tid + 1];
    ((uint32_t*)hv4[0])[tid] = __builtin_bit_cast(uint32_t, p2);
  }
  __syncthreads();

  int cb = 0;
  for (int s = 0; s < nsteps; ++s) {
    const int t = dir ? (TT - 1 - t0 - s) : (t0 + s);
    float gr, gz, gn;
    if (LAYER == 0) {
      float x0 = x[((size_t)b * TT + t) * 2 + 0];
      float x1 = x[((size_t)b * TT + t) * 2 + 1];
      gr = wi00 * x0 + wi01 * x1 + bi0;
      gz = wi10 * x0 + wi11 * x1 + bi1;
      gn = wi20 * x0 + wi21 * x1 + bi2;
    } else {
      const f16* g = gi + ((size_t)b * nsteps + s) * 1536 + dir * 768 + pair;
      gr = (float)g[0]; gz = (float)g[256]; gn = (float)g[512];
    }
    const uint4* hw = hv4[cb] + half * 16;
    float a0 = 0.f, a1 = 0.f, a2 = 0.f;
    float d0 = 0.f, d1 = 0.f, d2 = 0.f;
#pragma unroll
    for (int j = 0; j < 8; ++j) {
      uint4 hh = hw[j];
      a0 = fdot2u(w0[j].x, hh.x, a0); a0 = fdot2u(w0[j].y, hh.y, a0);
      a0 = fdot2u(w0[j].z, hh.z, a0); a0 = fdot2u(w0[j].w, hh.w, a0);
      a1 = fdot2u(w1[j].x, hh.x, a1); a1 = fdot2u(w1[j].y, hh.y, a1);
      a1 = fdot2u(w1[j].z, hh.z, a1); a1 = fdot2u(w1[j].w, hh.w, a1);
      a2 = fdot2u(w2[j].x, hh.x, a2); a2 = fdot2u(w2[j].y, hh.y, a2);
      a2 = fdot2u(w2[j].w, hh.w, a2); a2 = fdot2u(w2[j].z, hh.z, a2);
    }
#pragma unroll
    for (int j = 8; j < 16; ++j) {
      uint4 hh = hw[j];
      d0 = fdot2u(w0[j].x, hh.x, d0); d0 = fdot2u(w0[j].y, hh.y, d0);
      d0 = fdot2u(w0[j].z, hh.z, d0); d0 = fdot2u(w0[j].w, hh.w, d0);
      d1 = fdot2u(w1[j].x, hh.x, d1); d1 = fdot2u(w1[j].y, hh.y, d1);
      d1 = fdot2u(w1[j].z, hh.z, d1); d1 = fdot2u(w1[j].w, hh.w, d1);
      d2 = fdot2u(w2[j].x, hh.x, d2); d2 = fdot2u(w2[j].y, hh.y, d2);
      d2 = fdot2u(w2[j].z, hh.z, d2); d2 = fdot2u(w2[j].w, hh.w, d2);
    }
    a0 += d0; a1 += d1; a2 += d2;
    a0 += __shfl_xor(a0, 1);
    a1 += __shfl_xor(a1, 1);
    a2 += __shfl_xor(a2, 1);

    float r = sigm_(gr + a0 + bh0);
    float z = sigm_(gz + a1 + bh1);
    float n = tanhf(gn + r * (a2 + bh2));
    float hn = (1.0f - z) * n + z * hreg;
    hreg = hn;
    if (half == 0) {
      y[((size_t)b * TT + t) * 512 + dir * 256 + pair] = (f16)hn;
      ((f16*)hv4[cb ^ 1])[pair] = (f16)hn;   // write OTHER buffer
    }
    __syncthreads();
    cb ^= 1;
  }
  if (half == 0) hs[pair] = hreg;
}

// ---------------- f16 MFMA GEMM: C = Arows @ Bt^T + bias ---------------------
__global__ __launch_bounds__(256)
void k_gemm(const f16* __restrict__ A, const f16* __restrict__ Bt,
            f16* __restrict__ C, const float* __restrict__ bias,
            int K, int shift, long bstride, int inner, int ldc, int coloff)
{
  const int m0 = blockIdx.x * 64, n0 = blockIdx.y * 64;
  const int tid = threadIdx.x, lane = tid & 63, wv = tid >> 6;
  __shared__ __align__(16) f16 As[64 * 40];
  __shared__ __align__(16) f16 Bs[64 * 40];
  f32x4 acc[4] = {{0,0,0,0},{0,0,0,0},{0,0,0,0},{0,0,0,0}};
  const int lrow = tid >> 2, lseg = tid & 3;
  const int ml = lane & 15, quad = lane >> 4;
  const int r = m0 + lrow;
  const f16* arow = A + (long)(r >> shift) * bstride
                      + (long)(r & ((1 << shift) - 1)) * inner;
  const f16* brow = Bt + (size_t)(n0 + lrow) * K;
  for (int k0 = 0; k0 < K; k0 += 32) {
    uint4 av = *(const uint4*)(arow + k0 + lseg * 8);
    uint4 bv = *(const uint4*)(brow + k0 + lseg * 8);
    __syncthreads();
    *(uint4*)(As + lrow * 40 + lseg * 8) = av;
    *(uint4*)(Bs + lrow * 40 + lseg * 8) = bv;
    __syncthreads();
    f16x8 af = *(const f16x8*)(As + (wv * 16 + ml) * 40 + quad * 8);
#pragma unroll
    for (int ns = 0; ns < 4; ++ns) {
      f16x8 bf = *(const f16x8*)(Bs + (ns * 16 + ml) * 40 + quad * 8);
      acc[ns] = __builtin_amdgcn_mfma_f32_16x16x32_f16(af, bf, acc[ns], 0, 0, 0);
    }
  }
#pragma unroll
  for (int ns = 0; ns < 4; ++ns) {
#pragma unroll
    for (int rr = 0; rr < 4; ++rr) {
      int row = m0 + wv * 16 + quad * 4 + rr;
      int col = n0 + ns * 16 + ml;
      float v = acc[ns][rr];
      if (bias) v += bias[col];
      C[(size_t)row * ldc + coloff + col] = (f16)v;
    }
  }
}

// ---------------- gi0[v][row] = dWih0 @ emb[v] + dbih  (29 x 768, f32) -------
__global__ void k_gi0(const float* __restrict__ dWih0, const float* __restrict__ dbih,
                      const float* __restrict__ emb, float* __restrict__ gi0) {
  int i = blockIdx.x * 256 + threadIdx.x;
  if (i >= VV * 768) return;
  int v = i / 768, row = i - v * 768;
  float a = dbih[row];
#pragma unroll
  for (int e = 0; e < 8; ++e) a += dWih0[row * 8 + e] * emb[v * 8 + e];
  gi0[i] = a;
}

// ---- register-weight matvec: 3 rows in W[12] regs, h from LDS seg slice ----
static __device__ __forceinline__ void mv3r(const uint4 (&W)[12], const f16* __restrict__ hsh,
                                            int seg, float& g0, float& g1, float& g2) {
  const uint4* hv = (const uint4*)(hsh + seg * 32);
  uint4 hq[4];
#pragma unroll
  for (int j = 0; j < 4; ++j) hq[j] = hv[j];
#pragma unroll
  for (int j = 0; j < 4; ++j) {
    g0 = fdot2u(W[j].x, hq[j].x, g0); g0 = fdot2u(W[j].y, hq[j].y, g0);
    g0 = fdot2u(W[j].z, hq[j].z, g0); g0 = fdot2u(W[j].w, hq[j].w, g0);
    g1 = fdot2u(W[4+j].x, hq[j].x, g1); g1 = fdot2u(W[4+j].y, hq[j].y, g1);
    g1 = fdot2u(W[4+j].z, hq[j].z, g1); g1 = fdot2u(W[4+j].w, hq[j].w, g1);
    g2 = fdot2u(W[8+j].x, hq[j].x, g2); g2 = fdot2u(W[8+j].y, hq[j].y, g2);
    g2 = fdot2u(W[8+j].z, hq[j].z, g2); g2 = fdot2u(W[8+j].w, hq[j].w, g2);
  }
}
static __device__ __forceinline__ float mv1r(const uint4 (&W)[4], const f16* __restrict__ hsh,
                                             int seg) {
  const uint4* hv = (const uint4*)(hsh + seg * 32);
  float g = 0.f;
#pragma unroll
  for (int j = 0; j < 4; ++j) {
    uint4 hq = hv[j];
    g = fdot2u(W[j].x, hq.x, g); g = fdot2u(W[j].y, hq.y, g);
    g = fdot2u(W[j].z, hq.z, g); g = fdot2u(W[j].w, hq.w, g);
  }
  return g;
}

// -------- decoder LDS layout (dynamic, ~151 KB -> 1 WG/CU, 256 WGs) ----------
#define SM_ENC0   0          // b0 enc quarter: 128 rows x 512 B (XOR-swizzled)
#define SM_ENC1   65536      // b1
#define SM_ENCO   131072     // encOT[2][32][128] f16
#define SM_SC     147456     // sc[2][128] f32
#define SM_H0     148480     // h0buf[2][2][256] f16 (buf, batch)
#define SM_H1     150528
#define SM_Q      152576     // qsh[2][256] f16
#define SM_RED    153600     // f32[8]
#define SM_RED2   153632     // f32[8]
#define SM_CTXO   153664     // ctxO[2][4][32] f32
#define SM_LG     154688     // lg[2][32] f32
#define SM_TOTAL  154944

// ------ persistent decoder: 4 quarters x 64 batch-pairs = 256 WGs, 1/CU ------
// ALL per-thread weight slices live in VGPRs (loaded once): zero per-step
// weight traffic. Each WG serves TWO batches (b0=2p, b1=2p+1) with the same
// register weights. Exchange protocol = R14 (tagged packets, s_sleep polls),
// run per batch. XCD-grouped quarters (blk&7)>>1.
__global__ __launch_bounds__(512, 2)
void k_decoder(const f16* __restrict__ dwhh,   // (2,768,256)
               const f16* __restrict__ dwih1,  // (768,256)
               const f16* __restrict__ qw,     // (256,256)
               const f16* __restrict__ outw,   // (29,256)
               const f16* __restrict__ enc,    // (B,512,256)
               const f16* __restrict__ encO,   // (B,512,64): outWpad @ enc
               const float* __restrict__ gi0,  // (29,768)
               const float* __restrict__ dbih, // (2,768)
               const float* __restrict__ dbhh, // (2,768)
               const float* __restrict__ qb, const float* __restrict__ outb,
               const float* __restrict__ hs0, const float* __restrict__ hs1,
               const int* __restrict__ tseq,
               u64* __restrict__ xh0,          // (B,128) f16-pair packets
               u64* __restrict__ xh1,          // (B,128)
               u64* __restrict__ xq,           // (B,128)
               u64* __restrict__ xcm,          // (B,4,32)
               float* __restrict__ out)
{
  extern __shared__ __align__(16) char smem[];
  float* sc   = (float*)(smem + SM_SC);              // [2][128]
  f16* h0base = (f16*)(smem + SM_H0);                // [2][2][256]
  f16* h1base = (f16*)(smem + SM_H1);
  f16* qshb   = (f16*)(smem + SM_Q);                 // [2][256]
  float* red  = (float*)(smem + SM_RED);
  float* red2 = (float*)(smem + SM_RED2);
  float* ctxO = (float*)(smem + SM_CTXO);            // [2][4][32]
  float* lg   = (float*)(smem + SM_LG);              // [2][32]

  const int tid = threadIdx.x;
  const int blk = blockIdx.x;
  const int wq = (blk & 7) >> 1;                     // XCD-grouped quarter
  const int p  = ((blk >> 3) << 1) | (blk & 1);      // batch pair [0,64)
  const int b0 = 2 * p, b1 = 2 * p + 1;
  const int o8 = tid >> 3, seg = tid & 7, gout = wq * 64 + o8;
  const f16* dwhh1 = dwhh + (size_t)768 * 256;

  // ---- preload ALL weight slices into VGPRs (once) ----
  uint4 wA[12], wB[12], wC[12], wQr[4];
#pragma unroll
  for (int rr = 0; rr < 3; ++rr) {
    const uint4* p0 = (const uint4*)(dwhh  + (size_t)(gout + rr * 256) * 256 + seg * 32);
    const uint4* p1 = (const uint4*)(dwih1 + (size_t)(gout + rr * 256) * 256 + seg * 32);
    const uint4* p2 = (const uint4*)(dwhh1 + (size_t)(gout + rr * 256) * 256 + seg * 32);
#pragma unroll
    for (int j = 0; j < 4; ++j) { wA[rr*4+j] = p0[j]; wB[rr*4+j] = p1[j]; wC[rr*4+j] = p2[j]; }
  }
  {
    const uint4* pq = (const uint4*)(qw + (size_t)gout * 256 + seg * 32);
#pragma unroll
    for (int j = 0; j < 4; ++j) wQr[j] = pq[j];
  }

  u64* xh0b[2] = { xh0 + (size_t)b0 * 128, xh0 + (size_t)b1 * 128 };
  u64* xh1b[2] = { xh1 + (size_t)b0 * 128, xh1 + (size_t)b1 * 128 };
  u64* xqb[2]  = { xq  + (size_t)b0 * 128, xq  + (size_t)b1 * 128 };
  u64* xcmb[2] = { xcm + (size_t)b0 * 4 * 32, xcm + (size_t)b1 * 4 * 32 };

  // hoisted constants (per owner row gout)
  const float bh00 = dbhh[gout], bh01 = dbhh[gout + 256], bh02 = dbhh[gout + 512];
  const float bi10 = dbih[768 + gout], bi11 = dbih[768 + gout + 256], bi12 = dbih[768 + gout + 512];
  const float bh10 = dbhh[768 + gout], bh11 = dbhh[768 + gout + 256], bh12 = dbhh[768 + gout + 512];
  const float qbv = qb[gout];
  float h0own[2], h1own[2];
  h0own[0] = hs0[b0 * 256 + gout] + hs0[32768 + b0 * 256 + gout];
  h0own[1] = hs0[b1 * 256 + gout] + hs0[32768 + b1 * 256 + gout];
  h1own[0] = hs1[b0 * 256 + gout] + hs1[32768 + b0 * 256 + gout];
  h1own[1] = hs1[b1 * 256 + gout] + hs1[32768 + b1 * 256 + gout];
  // logits weights in registers
  const int lv_ = tid >> 4, lk_ = tid & 15;
  uint4 ow0 = {0,0,0,0}, ow1 = {0,0,0,0}; float outbv = 0.f;
  if (tid < VV * 16) {
    const uint4* owp = (const uint4*)(outw + (size_t)lv_ * 256 + lk_ * 16);
    ow0 = owp[0]; ow1 = owp[1];
    outbv = outb[lv_];
  }
  if (tid < 256) {
#pragma unroll
    for (int bb = 0; bb < 2; ++bb) {
      int bx = bb ? b1 : b0;
      h0base[bb * 256 + tid] = (f16)(hs0[bx * 256 + tid] + hs0[32768 + bx * 256 + tid]);
      h1base[bb * 256 + tid] = (f16)(hs1[bx * 256 + tid] + hs1[32768 + bx * 256 + tid]);
    }
  }
  // fill enc quarters for both batches: rows [wq*128,+128), XOR-swizzled
#pragma unroll
  for (int bb = 0; bb < 2; ++bb) {
    const int bx = bb ? b1 : b0;
    const int r = tid >> 2, q8 = tid & 3;
    const uint4* src = (const uint4*)(enc + ((size_t)bx * 512 + wq * 128 + r) * 256) + q8 * 8;
    const int sw = (r & 31) << 4;
#pragma unroll
    for (int j = 0; j < 8; ++j) {
      uint4 v = src[j];
      *(uint4*)(smem + bb * 65536 + r * 512 + (((q8 * 8 + j) * 16) ^ sw)) = v;
    }
  }
  // fill encOT for both batches
#pragma unroll
  for (int bb = 0; bb < 2; ++bb) {
    const int bx = bb ? b1 : b0;
    f16* eo = (f16*)(smem + SM_ENCO) + bb * 4096;
    const int r = tid >> 2, g = tid & 3;
    if (g < 2) {
      const uint4* src = (const uint4*)(encO + ((size_t)bx * 512 + wq * 128 + r) * 64 + g * 16);
#pragma unroll
      for (int u = 0; u < 2; ++u) {
        uint4 v = src[u];
        const f16* vp = (const f16*)&v;
#pragma unroll
        for (int j = 0; j < 8; ++j) eo[(g * 16 + u * 8 + j) * 128 + r] = vp[j];
      }
    }
  }
  int tok[2] = { tseq[b0 * 64], tseq[b1 * 64] };
  __syncthreads();

  for (int s = 0; s < NSTEP; ++s) {
    const int cur = s & 1, nxt = cur ^ 1;
    const unsigned tag = (unsigned)(s + 1);

    // ---- P1 cell0: register weights, both batches ----
#pragma unroll
    for (int bb = 0; bb < 2; ++bb) {
      float g0 = 0.f, g1 = 0.f, g2 = 0.f;
      mv3r(wA, h0base + (cur * 2 + bb) * 256, seg, g0, g1, g2);
      g0 += __shfl_xor(g0, 1); g0 += __shfl_xor(g0, 2); g0 += __shfl_xor(g0, 4);
      g1 += __shfl_xor(g1, 1); g1 += __shfl_xor(g1, 2); g1 += __shfl_xor(g1, 4);
      g2 += __shfl_xor(g2, 1); g2 += __shfl_xor(g2, 2); g2 += __shfl_xor(g2, 4);
      if (seg == 0) {
        const float* giP = gi0 + tok[bb] * 768;
        float r = sigm_(giP[gout] + g0 + bh00);
        float z = sigm_(giP[gout + 256] + g1 + bh01);
        float n = tanhf(giP[gout + 512] + r * (g2 + bh02));
        h0own[bb] = (1.f - z) * n + z * h0own[bb];
      }
      float pnext = __shfl_down(h0own[bb], 8);
      if (seg == 0 && !(o8 & 1))
        pubp(xh0b[bb] + (gout >> 1), tag, pack2h(h0own[bb], pnext));
    }
    if (tid < 128)
      ((uint32_t*)(h0base + (nxt * 2 + 0) * 256))[tid] = pollp(xh0b[0] + tid, tag);
    else if (tid < 256)
      ((uint32_t*)(h0base + (nxt * 2 + 1) * 256))[tid - 128] = pollp(xh0b[1] + (tid - 128), tag);
    __syncthreads();             // B1

    // ---- P2 cell1: register weights, both batches ----
#pragma unroll
    for (int bb = 0; bb < 2; ++bb) {
      float a0 = 0.f, a1 = 0.f, a2 = 0.f;
      mv3r(wB, h0base + (nxt * 2 + bb) * 256, seg, a0, a1, a2);
      float c0 = 0.f, c1 = 0.f, c2 = 0.f;
      mv3r(wC, h1base + (cur * 2 + bb) * 256, seg, c0, c1, c2);
      a0 += __shfl_xor(a0, 1); a0 += __shfl_xor(a0, 2); a0 += __shfl_xor(a0, 4);
      a1 += __shfl_xor(a1, 1); a1 += __shfl_xor(a1, 2); a1 += __shfl_xor(a1, 4);
      a2 += __shfl_xor(a2, 1); a2 += __shfl_xor(a2, 2); a2 += __shfl_xor(a2, 4);
      c0 += __shfl_xor(c0, 1); c0 += __shfl_xor(c0, 2); c0 += __shfl_xor(c0, 4);
      c1 += __shfl_xor(c1, 1); c1 += __shfl_xor(c1, 2); c1 += __shfl_xor(c1, 4);
      c2 += __shfl_xor(c2, 1); c2 += __shfl_xor(c2, 2); c2 += __shfl_xor(c2, 4);
      if (seg == 0) {
        float r = sigm_(a0 + bi10 + c0 + bh10);
        float z = sigm_(a1 + bi11 + c1 + bh11);
        float n = tanhf(a2 + bi12 + r * (c2 + bh12));
        h1own[bb] = (1.f - z) * n + z * h1own[bb];
      }
      float pnext = __shfl_down(h1own[bb], 8);
      if (seg == 0 && !(o8 & 1))
        pubp(xh1b[bb] + (gout >> 1), tag, pack2h(h1own[bb], pnext));
    }
    if (tid < 128)
      ((uint32_t*)(h1base + (nxt * 2 + 0) * 256))[tid] = pollp(xh1b[0] + tid, tag);
    else if (tid < 256)
      ((uint32_t*)(h1base + (nxt * 2 + 1) * 256))[tid - 128] = pollp(xh1b[1] + (tid - 128), tag);
    __syncthreads();             // B2

    // ---- P3 q: register weights, both batches ----
#pragma unroll
    for (int bb = 0; bb < 2; ++bb) {
      float qv = mv1r(wQr, h1base + (nxt * 2 + bb) * 256, seg);
      qv += __shfl_xor(qv, 1); qv += __shfl_xor(qv, 2); qv += __shfl_xor(qv, 4);
      qv += qbv;
      float pnext = __shfl_down(qv, 8);
      if (seg == 0 && !(o8 & 1))
        pubp(xqb[bb] + (gout >> 1), tag, pack2h(qv, pnext));
    }
    if (tid < 128)
      ((uint32_t*)(qshb + 0))[tid] = pollp(xqb[0] + tid, tag);
    else if (tid < 256)
      ((uint32_t*)(qshb + 256))[tid - 128] = pollp(xqb[1] + (tid - 128), tag);
    __syncthreads();             // B3

    // ---- P4 scores over MY 128 LDS enc rows, both batches ----
#pragma unroll
    for (int bb = 0; bb < 2; ++bb) {
      const int r = tid >> 2, sg = tid & 3;
      const int sw = (r & 31) << 4;
      const uint4* q4 = (const uint4*)(qshb + bb * 256);
      float s0 = 0.f, s1 = 0.f;
#pragma unroll
      for (int j = 0; j < 8; ++j) {
        int sgi = sg * 8 + j;
        uint4 ev = *(const uint4*)(smem + bb * 65536 + r * 512 + ((sgi * 16) ^ sw));
        uint4 qv = q4[sgi];
        s0 = fdot2u(ev.x, qv.x, s0); s0 = fdot2u(ev.y, qv.y, s0);
        s1 = fdot2u(ev.z, qv.z, s1); s1 = fdot2u(ev.w, qv.w, s1);
      }
      float sv = s0 + s1;
      sv += __shfl_xor(sv, 1); sv += __shfl_xor(sv, 2);
      if (sg == 0) sc[bb * 128 + r] = sv;
    }
    __syncthreads();             // B4

    // ---- local softmax stats, both batches in parallel (waves 0-3) ----
    float m_b[2], l_b[2];
    {
      const int bb = (tid >> 7) & 1;
      float v = (tid < 256) ? sc[bb * 128 + (tid & 127)] : -3.4e38f;
      float mloc = v;
#pragma unroll
      for (int off = 32; off; off >>= 1) mloc = fmaxf(mloc, __shfl_xor(mloc, off));
      if (tid < 256 && (tid & 63) == 0) red[tid >> 6] = mloc;
      __syncthreads();           // B5
      m_b[0] = fmaxf(red[0], red[1]);
      m_b[1] = fmaxf(red[2], red[3]);
      float e = 0.f;
      if (tid < 256) { e = __expf(v - m_b[bb]); sc[bb * 128 + (tid & 127)] = e; }
      float ls = e;
#pragma unroll
      for (int off = 32; off; off >>= 1) ls += __shfl_xor(ls, off);
      if (tid < 256 && (tid & 63) == 0) red2[tid >> 6] = ls;
      __syncthreads();           // B6
      l_b[0] = red2[0] + red2[1];
      l_b[1] = red2[2] + red2[3];
    }

    // ---- P5 weighted-encO partials (29) + (m,l) pubs, both batches ----
#pragma unroll
    for (int bb = 0; bb < 2; ++bb) {
      const int oo = tid >> 4, tk = tid & 15;
      if (oo < VV) {
        const f16* eo = (const f16*)(smem + SM_ENCO) + bb * 4096;
        uint4 ev = *(const uint4*)(eo + oo * 128 + tk * 8);
        const f16* ep = (const f16*)&ev;
        const float* wp = sc + bb * 128 + tk * 8;
        float a = 0.f;
#pragma unroll
        for (int j = 0; j < 8; ++j) a += wp[j] * (float)ep[j];
        a += __shfl_xor(a, 1); a += __shfl_xor(a, 2);
        a += __shfl_xor(a, 4); a += __shfl_xor(a, 8);
        if (tk == 0) pubf(xcmb[bb] + wq * 32 + oo, tag, a);
      }
      if (tid == 480) pubf(xcmb[bb] + wq * 32 + 29, tag, m_b[bb]);
      if (tid == 481) pubf(xcmb[bb] + wq * 32 + 30, tag, l_b[bb]);
    }
    if (tid < 128) {
      const int q4 = tid >> 5, ix = tid & 31;
      if (ix < 31) ctxO[0 * 128 + q4 * 32 + ix] = pollf(xcmb[0] + q4 * 32 + ix, tag);
    } else if (tid < 256) {
      const int t2 = tid - 128;
      const int q4 = t2 >> 5, ix = t2 & 31;
      if (ix < 31) ctxO[1 * 128 + q4 * 32 + ix] = pollf(xcmb[1] + q4 * 32 + ix, tag);
    }
    __syncthreads();             // B7

    // ---- P6 logits, both batches ----
    if (tid < VV * 16) {
#pragma unroll
      for (int bb = 0; bb < 2; ++bb) {
        const uint32_t* h1u = (const uint32_t*)(h1base + (nxt * 2 + bb) * 256) + lk_ * 8;
        float acc = 0.f;
        acc = fdot2u(ow0.x, h1u[0], acc); acc = fdot2u(ow0.y, h1u[1], acc);
        acc = fdot2u(ow0.z, h1u[2], acc); acc = fdot2u(ow0.w, h1u[3], acc);
        acc = fdot2u(ow1.x, h1u[4], acc); acc = fdot2u(ow1.y, h1u[5], acc);
        acc = fdot2u(ow1.z, h1u[6], acc); acc = fdot2u(ow1.w, h1u[7], acc);
        acc += __shfl_xor(acc, 1); acc += __shfl_xor(acc, 2);
        acc += __shfl_xor(acc, 4); acc += __shfl_xor(acc, 8);
        if (lk_ == 0) {
          const float* cO = ctxO + bb * 128;
          float m0 = cO[29], m1 = cO[32 + 29], m2 = cO[64 + 29], m3 = cO[96 + 29];
          float m = fmaxf(fmaxf(m0, m1), fmaxf(m2, m3));
          float w0 = __expf(m0 - m), w1 = __expf(m1 - m);
          float w2 = __expf(m2 - m), w3 = __expf(m3 - m);
          float l = cO[30] * w0 + cO[32 + 30] * w1 + cO[64 + 30] * w2 + cO[96 + 30] * w3;
          float cs = cO[lv_] * w0 + cO[32 + lv_] * w1 + cO[64 + lv_] * w2 + cO[96 + lv_] * w3;
          float lvv = acc + cs / l + outbv;
          lg[bb * 32 + lv_] = lvv;
          if (wq == 0) {
            int bx = bb ? b1 : b0;
            out[((size_t)bx * NSTEP + s) * VV + lv_] = lvv;
          }
        }
      }
    }
    __syncthreads();             // B8

    // ---- argmax for both batches (replicated in every wave) ----
    {
      const int lane = tid & 63;
#pragma unroll
      for (int bb = 0; bb < 2; ++bb) {
        float val = (lane < VV) ? lg[bb * 32 + lane] : -3.4e38f;
        int bi = lane;
#pragma unroll
        for (int off = 32; off; off >>= 1) {
          float ov = __shfl_xor(val, off);
          int oi = __shfl_xor(bi, off);
          if (ov > val || (ov == val && oi < bi)) { val = ov; bi = oi; }
        }
        tok[bb] = bi;
      }
    }
  }

  // final hidden
  if (wq == 0 && tid < 256) {
    const int fb = NSTEP & 1;
#pragma unroll
    for (int bb = 0; bb < 2; ++bb) {
      int bx = bb ? b1 : b0;
      out[233856 + bx * 256 + tid] = (float)h0base[(fb * 2 + bb) * 256 + tid];
      out[233856 + 32768 + bx * 256 + tid] = (float)h1base[(fb * 2 + bb) * 256 + tid];
    }
  }
}

extern "C" void kernel_launch(void* const* d_in, const int* in_sizes, int n_in,
                              void* d_out, int out_size, void* d_ws, size_t ws_size,
                              hipStream_t stream) {
  (void)in_sizes; (void)n_in; (void)out_size; (void)ws_size;
  const float* x     = (const float*)d_in[0];
  const int*   tseq  = (const int*)d_in[1];
  const float* eWih0 = (const float*)d_in[2];
  const float* eWhh0 = (const float*)d_in[3];
  const float* ebih0 = (const float*)d_in[4];
  const float* ebhh0 = (const float*)d_in[5];
  const float* eWih1 = (const float*)d_in[6];
  const float* eWhh1 = (const float*)d_in[7];
  const float* ebih1 = (const float*)d_in[8];
  const float* ebhh1 = (const float*)d_in[9];
  const float* e2dW  = (const float*)d_in[10];
  const float* e2db  = (const float*)d_in[11];
  const float* dWih0 = (const float*)d_in[12];
  const float* dWih1 = (const float*)d_in[13];
  const float* dWhh  = (const float*)d_in[14];
  const float* dbih  = (const float*)d_in[15];
  const float* dbhh  = (const float*)d_in[16];
  const float* qW    = (const float*)d_in[17];
  const float* qb    = (const float*)d_in[18];
  const float* outW  = (const float*)d_in[19];
  const float* outb  = (const float*)d_in[20];
  const float* emb   = (const float*)d_in[21];

  // ---- workspace ledger ----
  uint8_t* ws = (uint8_t*)d_ws;
  size_t o = 0;
  auto take = [&](size_t bytes) -> void* {
    void* p = ws + o;
    o += (bytes + 255) & ~(size_t)255;
    return p;
  };
  f16* whh0_16  = (f16*)take((size_t)2 * 768 * 256 * 2);
  f16* whh1_16  = (f16*)take((size_t)2 * 768 * 256 * 2);
  f16* wih1_16  = (f16*)take((size_t)2 * 768 * 512 * 2);
  f16* e2d_16   = (f16*)take((size_t)256 * 512 * 2);
  f16* qw_16    = (f16*)take((size_t)256 * 256 * 2);
  f16* outw_16  = (f16*)take((size_t)29 * 256 * 2);
  f16* owpad_16 = (f16*)take((size_t)64 * 256 * 2);
  f16* dwih1_16 = (f16*)take((size_t)768 * 256 * 2);
  f16* dwhh_16  = (f16*)take((size_t)2 * 768 * 256 * 2);
  f16* y0   = (f16*)take((size_t)BT * 512 * 2);          // enc aliases later
  f16* y1   = (f16*)take((size_t)BT * 512 * 2);
  f16* gi   = (f16*)take((size_t)BB * CHUNK * 1536 * 2); // encO aliases later
  float* hs0 = (float*)take((size_t)2 * BB * 256 * 4);
  float* hs1 = (float*)take((size_t)2 * BB * 256 * 4);
  float* gi0 = (float*)take((size_t)VV * 768 * 4);
  u64* xh0  = (u64*)take((size_t)BB * 128 * 8);
  u64* xh1  = (u64*)take((size_t)BB * 128 * 8);
  u64* xq   = (u64*)take((size_t)BB * 128 * 8);
  u64* xcm  = (u64*)take((size_t)BB * 4 * 32 * 8);
  f16* enc  = y0;  // alias: y0 dead after last gi chunk GEMM
  f16* encO = (f16*)gi;  // alias: gi dead after last k_scan<1>

  hipMemsetAsync(hs0, 0, (size_t)2 * BB * 256 * 4, stream);
  hipMemsetAsync(hs1, 0, (size_t)2 * BB * 256 * 4, stream);
  hipMemsetAsync(xh0, 0, (size_t)BB * 128 * 8, stream);
  hipMemsetAsync(xh1, 0, (size_t)BB * 128 * 8, stream);
  hipMemsetAsync(xq,  0, (size_t)BB * 128 * 8, stream);
  hipMemsetAsync(xcm, 0, (size_t)BB * 4 * 32 * 8, stream);
  hipMemsetAsync(owpad_16, 0, (size_t)64 * 256 * 2, stream);

  auto cvt = [&](const float* s, f16* d, int n) {
    k_cvt<<<(n + 255) / 256, 256, 0, stream>>>(s, d, n);
  };
  cvt(eWhh0, whh0_16, 2 * 768 * 256);
  cvt(eWhh1, whh1_16, 2 * 768 * 256);
  cvt(eWih1, wih1_16, 2 * 768 * 512);
  cvt(e2dW,  e2d_16,  256 * 512);
  cvt(qW,    qw_16,   256 * 256);
  cvt(outW,  outw_16, 29 * 256);
  cvt(outW,  owpad_16, 29 * 256);
  cvt(dWih1, dwih1_16, 768 * 256);
  cvt(dWhh,  dwhh_16, 2 * 768 * 256);
  k_gi0<<<(VV * 768 + 255) / 256, 256, 0, stream>>>(dWih0, dbih, emb, gi0);

  // encoder layer 0
  k_scan<0><<<256, 512, 0, stream>>>(x, nullptr, (const uint32_t*)whh0_16,
                                     eWih0, ebih0, ebhh0, y0, hs0, 0, TT);

  // encoder layer 1: time-chunked gi GEMM + scan
  const long BSTR = (long)TT * 512;
  for (int c = 0; c < TT / CHUNK; ++c) {
    const int t0 = c * CHUNK;
    k_gemm<<<dim3(BB * CHUNK / 64, 12), 256, 0, stream>>>(
        y0 + (size_t)t0 * 512, wih1_16, gi, ebih1,
        512, 6, BSTR, 512, 1536, 0);
    k_gemm<<<dim3(BB * CHUNK / 64, 12), 256, 0, stream>>>(
        y0 + (size_t)(TT - 1 - t0) * 512, wih1_16 + (size_t)768 * 512, gi, ebih1 + 768,
        512, 6, BSTR, -512, 1536, 768);
    k_scan<1><<<256, 512, 0, stream>>>(nullptr, gi, (const uint32_t*)whh1_16,
                                       nullptr, nullptr, ebhh1, y1, hs1, t0, CHUNK);
  }

  // enc = y1 @ e2d^T + b   (writes into y0's region)
  k_gemm<<<dim3(BT / 64, 4), 256, 0, stream>>>(y1, e2d_16, enc, e2db,
                                               512, 30, 0, 512, 256, 0);

  // encO = enc @ outWpad^T  (BT x 64, f16)  — writes into gi's region
  k_gemm<<<dim3(BT / 64, 1), 256, 0, stream>>>(enc, owpad_16, encO, nullptr,
                                               256, 30, 0, 256, 64, 0);

  // persistent decoder: 256 WGs (4 quarters x 64 batch-pairs), 1 WG/CU
  hipFuncSetAttribute((const void*)k_decoder,
                      hipFuncAttributeMaxDynamicSharedMemorySize, SM_TOTAL);
  k_decoder<<<256, 512, SM_TOTAL, stream>>>(dwhh_16, dwih1_16, qw_16, outw_16,
                                            enc, encO, gi0, dbih, dbhh, qb, outb,
                                            hs0, hs1, tseq,
                                            xh0, xh1, xq, xcm,
                                            (float*)d_out);
}

// Round 17
// 2712.009 us; speedup vs baseline: 1.7910x; 1.1985x over previous
//
#include <hip/hip_runtime.h>
#include <hip/hip_bf16.h>
#include <hip/hip_fp16.h>
#include <stdint.h>

// Problem dims
#define BB 128
#define TT 512
#define HH 256
#define VV 29
#define NSTEP 63
#define BT (BB*TT)
#define CHUNK 64   // layer-1 time chunk
#define GQ 4       // decoder quarters per batch

typedef _Float16 f16;
typedef _Float16 f16x2 __attribute__((ext_vector_type(2)));
typedef _Float16 f16x8 __attribute__((ext_vector_type(8)));
typedef float f32x4 __attribute__((ext_vector_type(4)));
typedef unsigned long long u64;

static __device__ __forceinline__ float fdot2u(uint32_t a, uint32_t b, float c) {
  return __builtin_amdgcn_fdot2(__builtin_bit_cast(f16x2, a),
                                __builtin_bit_cast(f16x2, b), c, false);
}
static __device__ __forceinline__ float sigm_(float x) {
  return 1.0f / (1.0f + __expf(-x));
}
// tagged exchange: (tag<<32)|payload32 in one relaxed agent-scope atomic.
// Poll backoff s_sleep(2): retries are cheap now (tiny exchange footprint).
static __device__ __forceinline__ void pubp(u64* p, unsigned tag, uint32_t pay) {
  u64 pkt = ((u64)tag << 32) | (u64)pay;
  (void)__hip_atomic_exchange(p, pkt, __ATOMIC_RELAXED, __HIP_MEMORY_SCOPE_AGENT);
}
static __device__ __forceinline__ uint32_t pollp(const u64* p, unsigned tag) {
  u64 pkt = __hip_atomic_load(p, __ATOMIC_RELAXED, __HIP_MEMORY_SCOPE_AGENT);
  while ((unsigned)(pkt >> 32) < tag) {
    __builtin_amdgcn_s_sleep(2);
    pkt = __hip_atomic_load(p, __ATOMIC_RELAXED, __HIP_MEMORY_SCOPE_AGENT);
  }
  return (uint32_t)pkt;
}
static __device__ __forceinline__ void pubf(u64* p, unsigned tag, float v) {
  pubp(p, tag, __builtin_bit_cast(uint32_t, v));
}
static __device__ __forceinline__ float pollf(const u64* p, unsigned tag) {
  return __builtin_bit_cast(float, pollp(p, tag));
}
static __device__ __forceinline__ uint32_t pack2h(float a, float b) {
  unsigned short ua = __builtin_bit_cast(unsigned short, (f16)a);
  unsigned short ub = __builtin_bit_cast(unsigned short, (f16)b);
  return (uint32_t)ua | ((uint32_t)ub << 16);
}

// ---------------- fp32 -> f16 convert ----------------
__global__ void k_cvt(const float* __restrict__ s, f16* __restrict__ d, int n) {
  int i = blockIdx.x * 256 + threadIdx.x;
  if (i < n) d[i] = (f16)s[i];
}

// -------- eqb[b*512+t] = enc[b,t,:] . qb  (f32) ------------------------------
__global__ __launch_bounds__(256)
void k_eqb(const f16* __restrict__ enc, const float* __restrict__ qb,
           float* __restrict__ eqb) {
  const int row = blockIdx.x * 4 + (threadIdx.x >> 6);
  const int lane = threadIdx.x & 63;
  const f16* e = enc + (size_t)row * 256 + lane * 4;
  float s = 0.f;
#pragma unroll
  for (int j = 0; j < 4; ++j) s += (float)e[j] * qb[lane * 4 + j];
#pragma unroll
  for (int off = 32; off; off >>= 1) s += __shfl_xor(s, off);
  if (lane == 0) eqb[row] = s;
}

// ---------------- persistent GRU scan: 1 WG per (batch, dir) ----------------
template<int LAYER>
__global__ __launch_bounds__(512, 2)
void k_scan(const float* __restrict__ x,        // L0: (B,T,2)
            const f16* __restrict__ gi,         // L1: (B,nsteps,1536) chunk-local
            const uint32_t* __restrict__ whh,   // (2,768,128) as half2
            const float* __restrict__ wih0,     // L0: (2,768,2)
            const float* __restrict__ bih,      // L0: (2,768)
            const float* __restrict__ bhh,      // (2,768)
            f16* __restrict__ y,                // (B,T,512) [t][dir*256+p]
            float* __restrict__ hstate,         // (2,B,256) f32
            int t0, int nsteps)
{
  const int wg = blockIdx.x, b = wg >> 1, dir = wg & 1;
  const int tid = threadIdx.x, pair = tid >> 1, half = tid & 1;
  __shared__ __align__(16) uint4 hv4[2][32];   // h as f16[256], double-buffered

  uint4 w0[16], w1[16], w2[16];
  {
    const uint32_t* wp = whh + (size_t)dir * 768 * 128;
    const uint4* r0 = (const uint4*)(wp + (size_t)pair * 128 + half * 64);
    const uint4* r1 = (const uint4*)(wp + (size_t)(pair + 256) * 128 + half * 64);
    const uint4* r2 = (const uint4*)(wp + (size_t)(pair + 512) * 128 + half * 64);
#pragma unroll
    for (int i = 0; i < 16; i++) { w0[i] = r0[i]; w1[i] = r1[i]; w2[i] = r2[i]; }
  }
  const float bh0 = bhh[dir * 768 + pair];
  const float bh1 = bhh[dir * 768 + pair + 256];
  const float bh2 = bhh[dir * 768 + pair + 512];
  float bi0 = 0, bi1 = 0, bi2 = 0;
  float wi00 = 0, wi01 = 0, wi10 = 0, wi11 = 0, wi20 = 0, wi21 = 0;
  if (LAYER == 0) {
    bi0 = bih[dir * 768 + pair];
    bi1 = bih[dir * 768 + pair + 256];
    bi2 = bih[dir * 768 + pair + 512];
    wi00 = wih0[(dir * 768 + pair) * 2 + 0];
    wi01 = wih0[(dir * 768 + pair) * 2 + 1];
    wi10 = wih0[(dir * 768 + pair + 256) * 2 + 0];
    wi11 = wih0[(dir * 768 + pair + 256) * 2 + 1];
    wi20 = wih0[(dir * 768 + pair + 512) * 2 + 0];
    wi21 = wih0[(dir * 768 + pair + 512) * 2 + 1];
  }
  float* hs = hstate + ((size_t)dir * BB + b) * 256;
  float hreg = hs[pair];
  if (tid < 128) {
    f16x2 p2; p2[0] = (f16)hs[2 * tid]; p2[1] = (f16)hs[2 * tid + 1];
    ((uint32_t*)hv4[0])[tid] = __builtin_bit_cast(uint32_t, p2);
  }
  __syncthreads();

  int cb = 0;
  for (int s = 0; s < nsteps; ++s) {
    const int t = dir ? (TT - 1 - t0 - s) : (t0 + s);
    float gr, gz, gn;
    if (LAYER == 0) {
      float x0 = x[((size_t)b * TT + t) * 2 + 0];
      float x1 = x[((size_t)b * TT + t) * 2 + 1];
      gr = wi00 * x0 + wi01 * x1 + bi0;
      gz = wi10 * x0 + wi11 * x1 + bi1;
      gn = wi20 * x0 + wi21 * x1 + bi2;
    } else {
      const f16* g = gi + ((size_t)b * nsteps + s) * 1536 + dir * 768 + pair;
      gr = (float)g[0]; gz = (float)g[256]; gn = (float)g[512];
    }
    const uint4* hw = hv4[cb] + half * 16;
    float a0 = 0.f, a1 = 0.f, a2 = 0.f;
    float d0 = 0.f, d1 = 0.f, d2 = 0.f;
#pragma unroll
    for (int j = 0; j < 8; ++j) {
      uint4 hh = hw[j];
      a0 = fdot2u(w0[j].x, hh.x, a0); a0 = fdot2u(w0[j].y, hh.y, a0);
      a0 = fdot2u(w0[j].z, hh.z, a0); a0 = fdot2u(w0[j].w, hh.w, a0);
      a1 = fdot2u(w1[j].x, hh.x, a1); a1 = fdot2u(w1[j].y, hh.y, a1);
      a1 = fdot2u(w1[j].z, hh.z, a1); a1 = fdot2u(w1[j].w, hh.w, a1);
      a2 = fdot2u(w2[j].x, hh.x, a2); a2 = fdot2u(w2[j].y, hh.y, a2);
      a2 = fdot2u(w2[j].w, hh.w, a2); a2 = fdot2u(w2[j].z, hh.z, a2);
    }
#pragma unroll
    for (int j = 8; j < 16; ++j) {
      uint4 hh = hw[j];
      d0 = fdot2u(w0[j].x, hh.x, d0); d0 = fdot2u(w0[j].y, hh.y, d0);
      d0 = fdot2u(w0[j].z, hh.z, d0); d0 = fdot2u(w0[j].w, hh.w, d0);
      d1 = fdot2u(w1[j].x, hh.x, d1); d1 = fdot2u(w1[j].y, hh.y, d1);
      d1 = fdot2u(w1[j].z, hh.z, d1); d1 = fdot2u(w1[j].w, hh.w, d1);
      d2 = fdot2u(w2[j].x, hh.x, d2); d2 = fdot2u(w2[j].y, hh.y, d2);
      d2 = fdot2u(w2[j].z, hh.z, d2); d2 = fdot2u(w2[j].w, hh.w, d2);
    }
    a0 += d0; a1 += d1; a2 += d2;
    a0 += __shfl_xor(a0, 1);
    a1 += __shfl_xor(a1, 1);
    a2 += __shfl_xor(a2, 1);

    float r = sigm_(gr + a0 + bh0);
    float z = sigm_(gz + a1 + bh1);
    float n = tanhf(gn + r * (a2 + bh2));
    float hn = (1.0f - z) * n + z * hreg;
    hreg = hn;
    if (half == 0) {
      y[((size_t)b * TT + t) * 512 + dir * 256 + pair] = (f16)hn;
      ((f16*)hv4[cb ^ 1])[pair] = (f16)hn;   // write OTHER buffer
    }
    __syncthreads();
    cb ^= 1;
  }
  if (half == 0) hs[pair] = hreg;
}

// ---------------- f16 MFMA GEMM: C = Arows @ Bt^T + bias ---------------------
__global__ __launch_bounds__(256)
void k_gemm(const f16* __restrict__ A, const f16* __restrict__ Bt,
            f16* __restrict__ C, const float* __restrict__ bias,
            int K, int shift, long bstride, int inner, int ldc, int coloff)
{
  const int m0 = blockIdx.x * 64, n0 = blockIdx.y * 64;
  const int tid = threadIdx.x, lane = tid & 63, wv = tid >> 6;
  __shared__ __align__(16) f16 As[64 * 40];
  __shared__ __align__(16) f16 Bs[64 * 40];
  f32x4 acc[4] = {{0,0,0,0},{0,0,0,0},{0,0,0,0},{0,0,0,0}};
  const int lrow = tid >> 2, lseg = tid & 3;
  const int ml = lane & 15, quad = lane >> 4;
  const int r = m0 + lrow;
  const f16* arow = A + (long)(r >> shift) * bstride
                      + (long)(r & ((1 << shift) - 1)) * inner;
  const f16* brow = Bt + (size_t)(n0 + lrow) * K;
  for (int k0 = 0; k0 < K; k0 += 32) {
    uint4 av = *(const uint4*)(arow + k0 + lseg * 8);
    uint4 bv = *(const uint4*)(brow + k0 + lseg * 8);
    __syncthreads();
    *(uint4*)(As + lrow * 40 + lseg * 8) = av;
    *(uint4*)(Bs + lrow * 40 + lseg * 8) = bv;
    __syncthreads();
    f16x8 af = *(const f16x8*)(As + (wv * 16 + ml) * 40 + quad * 8);
#pragma unroll
    for (int ns = 0; ns < 4; ++ns) {
      f16x8 bf = *(const f16x8*)(Bs + (ns * 16 + ml) * 40 + quad * 8);
      acc[ns] = __builtin_amdgcn_mfma_f32_16x16x32_f16(af, bf, acc[ns], 0, 0, 0);
    }
  }
#pragma unroll
  for (int ns = 0; ns < 4; ++ns) {
#pragma unroll
    for (int rr = 0; rr < 4; ++rr) {
      int row = m0 + wv * 16 + quad * 4 + rr;
      int col = n0 + ns * 16 + ml;
      float v = acc[ns][rr];
      if (bias) v += bias[col];
      C[(size_t)row * ldc + coloff + col] = (f16)v;
    }
  }
}

// ---------------- gi0[v][row] = dWih0 @ emb[v] + dbih  (29 x 768, f32) -------
__global__ void k_gi0(const float* __restrict__ dWih0, const float* __restrict__ dbih,
                      const float* __restrict__ emb, float* __restrict__ gi0) {
  int i = blockIdx.x * 256 + threadIdx.x;
  if (i >= VV * 768) return;
  int v = i / 768, row = i - v * 768;
  float a = dbih[row];
#pragma unroll
  for (int e = 0; e < 8; ++e) a += dWih0[row * 8 + e] * emb[v * 8 + e];
  gi0[i] = a;
}

// ---- register-weight matvec: 3 rows in W[12] regs, h from LDS seg slice ----
static __device__ __forceinline__ void mv3r(const uint4 (&W)[12], const f16* __restrict__ hsh,
                                            int seg, float& g0, float& g1, float& g2) {
  const uint4* hv = (const uint4*)(hsh + seg * 32);
  uint4 hq[4];
#pragma unroll
  for (int j = 0; j < 4; ++j) hq[j] = hv[j];
#pragma unroll
  for (int j = 0; j < 4; ++j) {
    g0 = fdot2u(W[j].x, hq[j].x, g0); g0 = fdot2u(W[j].y, hq[j].y, g0);
    g0 = fdot2u(W[j].z, hq[j].z, g0); g0 = fdot2u(W[j].w, hq[j].w, g0);
    g1 = fdot2u(W[4+j].x, hq[j].x, g1); g1 = fdot2u(W[4+j].y, hq[j].y, g1);
    g1 = fdot2u(W[4+j].z, hq[j].z, g1); g1 = fdot2u(W[4+j].w, hq[j].w, g1);
    g2 = fdot2u(W[8+j].x, hq[j].x, g2); g2 = fdot2u(W[8+j].y, hq[j].y, g2);
    g2 = fdot2u(W[8+j].z, hq[j].z, g2); g2 = fdot2u(W[8+j].w, hq[j].w, g2);
  }
}

// -------- decoder LDS layout (dynamic, ~151 KB -> 1 WG/CU, 256 WGs) ----------
#define SM_ENCQ0  0          // b0 encQ quarter: 128 rows x 512 B (XOR-swizzled)
#define SM_ENCQ1  65536      // b1
#define SM_ENCO   131072     // encOT[2][32][128] f16
#define SM_SC     147456     // sc[2][128] f32
#define SM_H0     148480     // h0buf[2][2][256] f16 (buf, batch)
#define SM_H1     150528
#define SM_EQB    152576     // eqbL[2][128] f32
#define SM_RED    153600     // f32[8]
#define SM_RED2   153632     // f32[8]
#define SM_CTXO   153664     // ctxO[2][4][32] f32
#define SM_LG     154688     // lg[2][32] f32
#define SM_TOTAL  154944

// ------ persistent decoder: 4 quarters x 64 batch-pairs = 256 WGs, 1/CU ------
// Weights in VGPRs (R16). q round ELIMINATED via encQ = enc@qW^T precompute:
// score_t = encQ_t . h1' + eqb_t  -> 3 exchange rounds/step (h0, h1, ctx).
// Same-XCD grouping: all 4 quarters of a batch-pair on one XCD.
__global__ __launch_bounds__(512, 2)
void k_decoder(const f16* __restrict__ dwhh,   // (2,768,256)
               const f16* __restrict__ dwih1,  // (768,256)
               const f16* __restrict__ outw,   // (29,256)
               const f16* __restrict__ encQ,   // (B,512,256): enc @ qW^T
               const f16* __restrict__ encO,   // (B,512,64): outWpad @ enc
               const float* __restrict__ eqb,  // (B,512): enc . qb
               const float* __restrict__ gi0,  // (29,768)
               const float* __restrict__ dbih, // (2,768)
               const float* __restrict__ dbhh, // (2,768)
               const float* __restrict__ outb,
               const float* __restrict__ hs0, const float* __restrict__ hs1,
               const int* __restrict__ tseq,
               u64* __restrict__ xh0,          // (B,128) f16-pair packets
               u64* __restrict__ xh1,          // (B,128)
               u64* __restrict__ xcm,          // (B,4,32)
               float* __restrict__ out)
{
  extern __shared__ __align__(16) char smem[];
  float* sc   = (float*)(smem + SM_SC);              // [2][128]
  f16* h0base = (f16*)(smem + SM_H0);                // [2][2][256]
  f16* h1base = (f16*)(smem + SM_H1);
  float* eqbL = (float*)(smem + SM_EQB);             // [2][128]
  float* red  = (float*)(smem + SM_RED);
  float* red2 = (float*)(smem + SM_RED2);
  float* ctxO = (float*)(smem + SM_CTXO);            // [2][4][32]
  float* lg   = (float*)(smem + SM_LG);              // [2][32]

  const int tid = threadIdx.x;
  const int blk = blockIdx.x;
  // same-XCD grouping: XCD r = blk&7 hosts all 4 quarters of pairs r*8..r*8+7
  const int t_  = blk >> 3, r_ = blk & 7;
  const int wq = t_ & 3;
  const int p  = r_ * 8 + (t_ >> 2);                 // bijective, [0,64)
  const int b0 = 2 * p, b1 = 2 * p + 1;
  const int o8 = tid >> 3, seg = tid & 7, gout = wq * 64 + o8;
  const f16* dwhh1 = dwhh + (size_t)768 * 256;

  // ---- preload ALL weight slices into VGPRs (once) ----
  uint4 wA[12], wB[12], wC[12];
#pragma unroll
  for (int rr = 0; rr < 3; ++rr) {
    const uint4* p0 = (const uint4*)(dwhh  + (size_t)(gout + rr * 256) * 256 + seg * 32);
    const uint4* p1 = (const uint4*)(dwih1 + (size_t)(gout + rr * 256) * 256 + seg * 32);
    const uint4* p2 = (const uint4*)(dwhh1 + (size_t)(gout + rr * 256) * 256 + seg * 32);
#pragma unroll
    for (int j = 0; j < 4; ++j) { wA[rr*4+j] = p0[j]; wB[rr*4+j] = p1[j]; wC[rr*4+j] = p2[j]; }
  }

  u64* xh0b[2] = { xh0 + (size_t)b0 * 128, xh0 + (size_t)b1 * 128 };
  u64* xh1b[2] = { xh1 + (size_t)b0 * 128, xh1 + (size_t)b1 * 128 };
  u64* xcmb[2] = { xcm + (size_t)b0 * 4 * 32, xcm + (size_t)b1 * 4 * 32 };

  // hoisted constants (per owner row gout)
  const float bh00 = dbhh[gout], bh01 = dbhh[gout + 256], bh02 = dbhh[gout + 512];
  const float bi10 = dbih[768 + gout], bi11 = dbih[768 + gout + 256], bi12 = dbih[768 + gout + 512];
  const float bh10 = dbhh[768 + gout], bh11 = dbhh[768 + gout + 256], bh12 = dbhh[768 + gout + 512];
  float h0own[2], h1own[2];
  h0own[0] = hs0[b0 * 256 + gout] + hs0[32768 + b0 * 256 + gout];
  h0own[1] = hs0[b1 * 256 + gout] + hs0[32768 + b1 * 256 + gout];
  h1own[0] = hs1[b0 * 256 + gout] + hs1[32768 + b0 * 256 + gout];
  h1own[1] = hs1[b1 * 256 + gout] + hs1[32768 + b1 * 256 + gout];
  // logits weights in registers
  const int lv_ = tid >> 4, lk_ = tid & 15;
  uint4 ow0 = {0,0,0,0}, ow1 = {0,0,0,0}; float outbv = 0.f;
  if (tid < VV * 16) {
    const uint4* owp = (const uint4*)(outw + (size_t)lv_ * 256 + lk_ * 16);
    ow0 = owp[0]; ow1 = owp[1];
    outbv = outb[lv_];
  }
  if (tid < 256) {
#pragma unroll
    for (int bb = 0; bb < 2; ++bb) {
      int bx = bb ? b1 : b0;
      h0base[bb * 256 + tid] = (f16)(hs0[bx * 256 + tid] + hs0[32768 + bx * 256 + tid]);
      h1base[bb * 256 + tid] = (f16)(hs1[bx * 256 + tid] + hs1[32768 + bx * 256 + tid]);
    }
  }
  // fill encQ quarters for both batches: rows [wq*128,+128), XOR-swizzled
#pragma unroll
  for (int bb = 0; bb < 2; ++bb) {
    const int bx = bb ? b1 : b0;
    const int r = tid >> 2, q8 = tid & 3;
    const uint4* src = (const uint4*)(encQ + ((size_t)bx * 512 + wq * 128 + r) * 256) + q8 * 8;
    const int sw = (r & 31) << 4;
#pragma unroll
    for (int j = 0; j < 8; ++j) {
      uint4 v = src[j];
      *(uint4*)(smem + bb * 65536 + r * 512 + (((q8 * 8 + j) * 16) ^ sw)) = v;
    }
  }
  // fill encOT for both batches
#pragma unroll
  for (int bb = 0; bb < 2; ++bb) {
    const int bx = bb ? b1 : b0;
    f16* eo = (f16*)(smem + SM_ENCO) + bb * 4096;
    const int r = tid >> 2, g = tid & 3;
    if (g < 2) {
      const uint4* src = (const uint4*)(encO + ((size_t)bx * 512 + wq * 128 + r) * 64 + g * 16);
#pragma unroll
      for (int u = 0; u < 2; ++u) {
        uint4 v = src[u];
        const f16* vp = (const f16*)&v;
#pragma unroll
        for (int j = 0; j < 8; ++j) eo[(g * 16 + u * 8 + j) * 128 + r] = vp[j];
      }
    }
  }
  // fill eqb quarters
  if (tid < 128) eqbL[tid] = eqb[(size_t)b0 * 512 + wq * 128 + tid];
  else if (tid < 256) eqbL[tid] = eqb[(size_t)b1 * 512 + wq * 128 + (tid - 128)];
  int tok[2] = { tseq[b0 * 64], tseq[b1 * 64] };
  __syncthreads();

  for (int s = 0; s < NSTEP; ++s) {
    const int cur = s & 1, nxt = cur ^ 1;
    const unsigned tag = (unsigned)(s + 1);

    // ---- P1 cell0: register weights, both batches ----
#pragma unroll
    for (int bb = 0; bb < 2; ++bb) {
      float g0 = 0.f, g1 = 0.f, g2 = 0.f;
      mv3r(wA, h0base + (cur * 2 + bb) * 256, seg, g0, g1, g2);
      g0 += __shfl_xor(g0, 1); g0 += __shfl_xor(g0, 2); g0 += __shfl_xor(g0, 4);
      g1 += __shfl_xor(g1, 1); g1 += __shfl_xor(g1, 2); g1 += __shfl_xor(g1, 4);
      g2 += __shfl_xor(g2, 1); g2 += __shfl_xor(g2, 2); g2 += __shfl_xor(g2, 4);
      if (seg == 0) {
        const float* giP = gi0 + tok[bb] * 768;
        float r = sigm_(giP[gout] + g0 + bh00);
        float z = sigm_(giP[gout + 256] + g1 + bh01);
        float n = tanhf(giP[gout + 512] + r * (g2 + bh02));
        h0own[bb] = (1.f - z) * n + z * h0own[bb];
      }
      float pnext = __shfl_down(h0own[bb], 8);
      if (seg == 0 && !(o8 & 1))
        pubp(xh0b[bb] + (gout >> 1), tag, pack2h(h0own[bb], pnext));
    }
    if (tid < 128)
      ((uint32_t*)(h0base + (nxt * 2 + 0) * 256))[tid] = pollp(xh0b[0] + tid, tag);
    else if (tid < 256)
      ((uint32_t*)(h0base + (nxt * 2 + 1) * 256))[tid - 128] = pollp(xh0b[1] + (tid - 128), tag);
    __syncthreads();             // B1: h0' gathered

    // ---- P2 cell1: register weights, both batches ----
#pragma unroll
    for (int bb = 0; bb < 2; ++bb) {
      float a0 = 0.f, a1 = 0.f, a2 = 0.f;
      mv3r(wB, h0base + (nxt * 2 + bb) * 256, seg, a0, a1, a2);
      float c0 = 0.f, c1 = 0.f, c2 = 0.f;
      mv3r(wC, h1base + (cur * 2 + bb) * 256, seg, c0, c1, c2);
      a0 += __shfl_xor(a0, 1); a0 += __shfl_xor(a0, 2); a0 += __shfl_xor(a0, 4);
      a1 += __shfl_xor(a1, 1); a1 += __shfl_xor(a1, 2); a1 += __shfl_xor(a1, 4);
      a2 += __shfl_xor(a2, 1); a2 += __shfl_xor(a2, 2); a2 += __shfl_xor(a2, 4);
      c0 += __shfl_xor(c0, 1); c0 += __shfl_xor(c0, 2); c0 += __shfl_xor(c0, 4);
      c1 += __shfl_xor(c1, 1); c1 += __shfl_xor(c1, 2); c1 += __shfl_xor(c1, 4);
      c2 += __shfl_xor(c2, 1); c2 += __shfl_xor(c2, 2); c2 += __shfl_xor(c2, 4);
      if (seg == 0) {
        float r = sigm_(a0 + bi10 + c0 + bh10);
        float z = sigm_(a1 + bi11 + c1 + bh11);
        float n = tanhf(a2 + bi12 + r * (c2 + bh12));
        h1own[bb] = (1.f - z) * n + z * h1own[bb];
      }
      float pnext = __shfl_down(h1own[bb], 8);
      if (seg == 0 && !(o8 & 1))
        pubp(xh1b[bb] + (gout >> 1), tag, pack2h(h1own[bb], pnext));
    }
    if (tid < 128)
      ((uint32_t*)(h1base + (nxt * 2 + 0) * 256))[tid] = pollp(xh1b[0] + tid, tag);
    else if (tid < 256)
      ((uint32_t*)(h1base + (nxt * 2 + 1) * 256))[tid - 128] = pollp(xh1b[1] + (tid - 128), tag);
    __syncthreads();             // B2: h1' gathered

    // ---- P3 scores = encQ . h1' + eqb over MY 128 rows, both batches ----
#pragma unroll
    for (int bb = 0; bb < 2; ++bb) {
      const int r = tid >> 2, sg = tid & 3;
      const int sw = (r & 31) << 4;
      const uint4* q4 = (const uint4*)(h1base + (nxt * 2 + bb) * 256);
      float s0 = 0.f, s1 = 0.f;
#pragma unroll
      for (int j = 0; j < 8; ++j) {
        int sgi = sg * 8 + j;
        uint4 ev = *(const uint4*)(smem + bb * 65536 + r * 512 + ((sgi * 16) ^ sw));
        uint4 qv = q4[sgi];
        s0 = fdot2u(ev.x, qv.x, s0); s0 = fdot2u(ev.y, qv.y, s0);
        s1 = fdot2u(ev.z, qv.z, s1); s1 = fdot2u(ev.w, qv.w, s1);
      }
      float sv = s0 + s1;
      sv += __shfl_xor(sv, 1); sv += __shfl_xor(sv, 2);
      if (sg == 0) sc[bb * 128 + r] = sv + eqbL[bb * 128 + r];
    }
    __syncthreads();             // B3: sc ready

    // ---- local softmax stats, both batches in parallel (waves 0-3) ----
    float m_b[2], l_b[2];
    {
      const int bb = (tid >> 7) & 1;
      float v = (tid < 256) ? sc[bb * 128 + (tid & 127)] : -3.4e38f;
      float mloc = v;
#pragma unroll
      for (int off = 32; off; off >>= 1) mloc = fmaxf(mloc, __shfl_xor(mloc, off));
      if (tid < 256 && (tid & 63) == 0) red[tid >> 6] = mloc;
      __syncthreads();           // B4
      m_b[0] = fmaxf(red[0], red[1]);
      m_b[1] = fmaxf(red[2], red[3]);
      float e = 0.f;
      if (tid < 256) { e = __expf(v - m_b[bb]); sc[bb * 128 + (tid & 127)] = e; }
      float ls = e;
#pragma unroll
      for (int off = 32; off; off >>= 1) ls += __shfl_xor(ls, off);
      if (tid < 256 && (tid & 63) == 0) red2[tid >> 6] = ls;
      __syncthreads();           // B5
      l_b[0] = red2[0] + red2[1];
      l_b[1] = red2[2] + red2[3];
    }

    // ---- P4 weighted-encO partials (29) + (m,l) pubs, both batches ----
#pragma unroll
    for (int bb = 0; bb < 2; ++bb) {
      const int oo = tid >> 4, tk = tid & 15;
      if (oo < VV) {
        const f16* eo = (const f16*)(smem + SM_ENCO) + bb * 4096;
        uint4 ev = *(const uint4*)(eo + oo * 128 + tk * 8);
        const f16* ep = (const f16*)&ev;
        const float* wp = sc + bb * 128 + tk * 8;
        float a = 0.f;
#pragma unroll
        for (int j = 0; j < 8; ++j) a += wp[j] * (float)ep[j];
        a += __shfl_xor(a, 1); a += __shfl_xor(a, 2);
        a += __shfl_xor(a, 4); a += __shfl_xor(a, 8);
        if (tk == 0) pubf(xcmb[bb] + wq * 32 + oo, tag, a);
      }
      if (tid == 480) pubf(xcmb[bb] + wq * 32 + 29, tag, m_b[bb]);
      if (tid == 481) pubf(xcmb[bb] + wq * 32 + 30, tag, l_b[bb]);
    }
    if (tid < 128) {
      const int q4 = tid >> 5, ix = tid & 31;
      if (ix < 31) ctxO[0 * 128 + q4 * 32 + ix] = pollf(xcmb[0] + q4 * 32 + ix, tag);
    } else if (tid < 256) {
      const int t2 = tid - 128;
      const int q4 = t2 >> 5, ix = t2 & 31;
      if (ix < 31) ctxO[1 * 128 + q4 * 32 + ix] = pollf(xcmb[1] + q4 * 32 + ix, tag);
    }
    __syncthreads();             // B6: ctxO gathered

    // ---- P5 logits, both batches ----
    if (tid < VV * 16) {
#pragma unroll
      for (int bb = 0; bb < 2; ++bb) {
        const uint32_t* h1u = (const uint32_t*)(h1base + (nxt * 2 + bb) * 256) + lk_ * 8;
        float acc = 0.f;
        acc = fdot2u(ow0.x, h1u[0], acc); acc = fdot2u(ow0.y, h1u[1], acc);
        acc = fdot2u(ow0.z, h1u[2], acc); acc = fdot2u(ow0.w, h1u[3], acc);
        acc = fdot2u(ow1.x, h1u[4], acc); acc = fdot2u(ow1.y, h1u[5], acc);
        acc = fdot2u(ow1.z, h1u[6], acc); acc = fdot2u(ow1.w, h1u[7], acc);
        acc += __shfl_xor(acc, 1); acc += __shfl_xor(acc, 2);
        acc += __shfl_xor(acc, 4); acc += __shfl_xor(acc, 8);
        if (lk_ == 0) {
          const float* cO = ctxO + bb * 128;
          float m0 = cO[29], m1 = cO[32 + 29], m2 = cO[64 + 29], m3 = cO[96 + 29];
          float m = fmaxf(fmaxf(m0, m1), fmaxf(m2, m3));
          float w0 = __expf(m0 - m), w1 = __expf(m1 - m);
          float w2 = __expf(m2 - m), w3 = __expf(m3 - m);
          float l = cO[30] * w0 + cO[32 + 30] * w1 + cO[64 + 30] * w2 + cO[96 + 30] * w3;
          float cs = cO[lv_] * w0 + cO[32 + lv_] * w1 + cO[64 + lv_] * w2 + cO[96 + lv_] * w3;
          float lvv = acc + cs / l + outbv;
          lg[bb * 32 + lv_] = lvv;
          if (wq == 0) {
            int bx = bb ? b1 : b0;
            out[((size_t)bx * NSTEP + s) * VV + lv_] = lvv;
          }
        }
      }
    }
    __syncthreads();             // B7: lg ready

    // ---- argmax for both batches (replicated in every wave) ----
    {
      const int lane = tid & 63;
#pragma unroll
      for (int bb = 0; bb < 2; ++bb) {
        float val = (lane < VV) ? lg[bb * 32 + lane] : -3.4e38f;
        int bi = lane;
#pragma unroll
        for (int off = 32; off; off >>= 1) {
          float ov = __shfl_xor(val, off);
          int oi = __shfl_xor(bi, off);
          if (ov > val || (ov == val && oi < bi)) { val = ov; bi = oi; }
        }
        tok[bb] = bi;
      }
    }
  }

  // final hidden
  if (wq == 0 && tid < 256) {
    const int fb = NSTEP & 1;
#pragma unroll
    for (int bb = 0; bb < 2; ++bb) {
      int bx = bb ? b1 : b0;
      out[233856 + bx * 256 + tid] = (float)h0base[(fb * 2 + bb) * 256 + tid];
      out[233856 + 32768 + bx * 256 + tid] = (float)h1base[(fb * 2 + bb) * 256 + tid];
    }
  }
}

extern "C" void kernel_launch(void* const* d_in, const int* in_sizes, int n_in,
                              void* d_out, int out_size, void* d_ws, size_t ws_size,
                              hipStream_t stream) {
  (void)in_sizes; (void)n_in; (void)out_size; (void)ws_size;
  const float* x     = (const float*)d_in[0];
  const int*   tseq  = (const int*)d_in[1];
  const float* eWih0 = (const float*)d_in[2];
  const float* eWhh0 = (const float*)d_in[3];
  const float* ebih0 = (const float*)d_in[4];
  const float* ebhh0 = (const float*)d_in[5];
  const float* eWih1 = (const float*)d_in[6];
  const float* eWhh1 = (const float*)d_in[7];
  const float* ebih1 = (const float*)d_in[8];
  const float* ebhh1 = (const float*)d_in[9];
  const float* e2dW  = (const float*)d_in[10];
  const float* e2db  = (const float*)d_in[11];
  const float* dWih0 = (const float*)d_in[12];
  const float* dWih1 = (const float*)d_in[13];
  const float* dWhh  = (const float*)d_in[14];
  const float* dbih  = (const float*)d_in[15];
  const float* dbhh  = (const float*)d_in[16];
  const float* qW    = (const float*)d_in[17];
  const float* qb    = (const float*)d_in[18];
  const float* outW  = (const float*)d_in[19];
  const float* outb  = (const float*)d_in[20];
  const float* emb   = (const float*)d_in[21];

  // ---- workspace ledger ----
  uint8_t* ws = (uint8_t*)d_ws;
  size_t o = 0;
  auto take = [&](size_t bytes) -> void* {
    void* p = ws + o;
    o += (bytes + 255) & ~(size_t)255;
    return p;
  };
  f16* whh0_16  = (f16*)take((size_t)2 * 768 * 256 * 2);
  f16* whh1_16  = (f16*)take((size_t)2 * 768 * 256 * 2);
  f16* wih1_16  = (f16*)take((size_t)2 * 768 * 512 * 2);
  f16* e2d_16   = (f16*)take((size_t)256 * 512 * 2);
  f16* qw_16    = (f16*)take((size_t)256 * 256 * 2);
  f16* outw_16  = (f16*)take((size_t)29 * 256 * 2);
  f16* owpad_16 = (f16*)take((size_t)64 * 256 * 2);
  f16* dwih1_16 = (f16*)take((size_t)768 * 256 * 2);
  f16* dwhh_16  = (f16*)take((size_t)2 * 768 * 256 * 2);
  f16* y0   = (f16*)take((size_t)BT * 512 * 2);          // enc aliases later
  f16* y1   = (f16*)take((size_t)BT * 512 * 2);          // encQ aliases later
  f16* gi   = (f16*)take((size_t)BB * CHUNK * 1536 * 2); // encO aliases later
  float* hs0 = (float*)take((size_t)2 * BB * 256 * 4);
  float* hs1 = (float*)take((size_t)2 * BB * 256 * 4);
  float* gi0 = (float*)take((size_t)VV * 768 * 4);
  float* eqb = (float*)take((size_t)BT * 4);
  u64* xh0  = (u64*)take((size_t)BB * 128 * 8);
  u64* xh1  = (u64*)take((size_t)BB * 128 * 8);
  u64* xcm  = (u64*)take((size_t)BB * 4 * 32 * 8);
  f16* enc  = y0;        // alias: y0 dead after last gi chunk GEMM
  f16* encO = (f16*)gi;  // alias: gi dead after last k_scan<1>
  f16* encQ = y1;        // alias: y1 dead after e2d GEMM

  hipMemsetAsync(hs0, 0, (size_t)2 * BB * 256 * 4, stream);
  hipMemsetAsync(hs1, 0, (size_t)2 * BB * 256 * 4, stream);
  hipMemsetAsync(xh0, 0, (size_t)BB * 128 * 8, stream);
  hipMemsetAsync(xh1, 0, (size_t)BB * 128 * 8, stream);
  hipMemsetAsync(xcm, 0, (size_t)BB * 4 * 32 * 8, stream);
  hipMemsetAsync(owpad_16, 0, (size_t)64 * 256 * 2, stream);

  auto cvt = [&](const float* s, f16* d, int n) {
    k_cvt<<<(n + 255) / 256, 256, 0, stream>>>(s, d, n);
  };
  cvt(eWhh0, whh0_16, 2 * 768 * 256);
  cvt(eWhh1, whh1_16, 2 * 768 * 256);
  cvt(eWih1, wih1_16, 2 * 768 * 512);
  cvt(e2dW,  e2d_16,  256 * 512);
  cvt(qW,    qw_16,   256 * 256);
  cvt(outW,  outw_16, 29 * 256);
  cvt(outW,  owpad_16, 29 * 256);
  cvt(dWih1, dwih1_16, 768 * 256);
  cvt(dWhh,  dwhh_16, 2 * 768 * 256);
  k_gi0<<<(VV * 768 + 255) / 256, 256, 0, stream>>>(dWih0, dbih, emb, gi0);

  // encoder layer 0
  k_scan<0><<<256, 512, 0, stream>>>(x, nullptr, (const uint32_t*)whh0_16,
                                     eWih0, ebih0, ebhh0, y0, hs0, 0, TT);

  // encoder layer 1: time-chunked gi GEMM + scan
  const long BSTR = (long)TT * 512;
  for (int c = 0; c < TT / CHUNK; ++c) {
    const int t0 = c * CHUNK;
    k_gemm<<<dim3(BB * CHUNK / 64, 12), 256, 0, stream>>>(
        y0 + (size_t)t0 * 512, wih1_16, gi, ebih1,
        512, 6, BSTR, 512, 1536, 0);
    k_gemm<<<dim3(BB * CHUNK / 64, 12), 256, 0, stream>>>(
        y0 + (size_t)(TT - 1 - t0) * 512, wih1_16 + (size_t)768 * 512, gi, ebih1 + 768,
        512, 6, BSTR, -512, 1536, 768);
    k_scan<1><<<256, 512, 0, stream>>>(nullptr, gi, (const uint32_t*)whh1_16,
                                       nullptr, nullptr, ebhh1, y1, hs1, t0, CHUNK);
  }

  // enc = y1 @ e2d^T + b   (writes into y0's region)
  k_gemm<<<dim3(BT / 64, 4), 256, 0, stream>>>(y1, e2d_16, enc, e2db,
                                               512, 30, 0, 512, 256, 0);

  // encO = enc @ outWpad^T  (BT x 64, f16)  — into gi's region
  k_gemm<<<dim3(BT / 64, 1), 256, 0, stream>>>(enc, owpad_16, encO, nullptr,
                                               256, 30, 0, 256, 64, 0);

  // encQ = enc @ qW^T  (BT x 256, f16)  — into y1's region (y1 dead now)
  k_gemm<<<dim3(BT / 64, 4), 256, 0, stream>>>(enc, qw_16, encQ, nullptr,
                                               256, 30, 0, 256, 256, 0);

  // eqb = enc . qb  (BT f32)
  k_eqb<<<BT / 4, 256, 0, stream>>>(enc, qb, eqb);

  // persistent decoder: 256 WGs (4 quarters x 64 batch-pairs), 1 WG/CU
  hipFuncSetAttribute((const void*)k_decoder,
                      hipFuncAttributeMaxDynamicSharedMemorySize, SM_TOTAL);
  k_decoder<<<256, 512, SM_TOTAL, stream>>>(dwhh_16, dwih1_16, outw_16,
                                            encQ, encO, eqb, gi0, dbih, dbhh,
                                            outb, hs0, hs1, tseq,
                                            xh0, xh1, xcm,
                                            (float*)d_out);
}